// Round 5
// baseline (242.260 us; speedup 1.0000x reference)
//
#include <hip/hip_runtime.h>
#include <cstddef>

#define SEQLEN 32
#define BATCH  32768
#define POSE   34
#define PREDL  15

typedef __attribute__((ext_vector_type(8))) short short8;
typedef __attribute__((ext_vector_type(4))) float f32x4;
typedef union { short8 s8; unsigned u[4]; } pk8;

#define MF(a,b,c) __builtin_amdgcn_mfma_f32_16x16x32_bf16(a,b,c,0,0,0)

__device__ __forceinline__ float sigm(float x){ return __builtin_amdgcn_rcpf(1.0f+__expf(-x)); }
__device__ __forceinline__ float tanh_(float x){ return fmaf(2.0f, __builtin_amdgcn_rcpf(1.0f+__expf(-2.0f*x)), -1.0f); }
__device__ __forceinline__ unsigned short f2bf(float f){ __bf16 b=(__bf16)f; return __builtin_bit_cast(unsigned short,b); }
__device__ __forceinline__ unsigned f22bf(float lo,float hi){ return (unsigned)f2bf(lo) | ((unsigned)f2bf(hi)<<16); }

__device__ __forceinline__ short8 zero8(){ pk8 r; r.u[0]=0;r.u[1]=0;r.u[2]=0;r.u[3]=0; return r.s8; }
// 8 consecutive global floats -> bf16x8 (one-time weight gathers)
__device__ __forceinline__ short8 g8(const float* __restrict__ p){
    pk8 r;
    float2 q0=*(const float2*)p, q1=*(const float2*)(p+2);
    float2 q2=*(const float2*)(p+4), q3=*(const float2*)(p+6);
    r.u[0]=f22bf(q0.x,q0.y); r.u[1]=f22bf(q1.x,q1.y);
    r.u[2]=f22bf(q2.x,q2.y); r.u[3]=f22bf(q3.x,q3.y);
    return r.s8;
}
// K64 B-frag chunk1 per g: [W32,W33,bias,0..] / Whh[0..8) / Whh[8..16) / 0
__device__ __forceinline__ short8 gW1(const float* __restrict__ Wih,const float* __restrict__ Whh,
                                      const float* __restrict__ bih,const float* __restrict__ bhh,
                                      int R,int g){
    if(g==0){ pk8 r; r.u[0]=f22bf(Wih[R*34+32],Wih[R*34+33]);
              r.u[1]=(unsigned)f2bf(bih[R]+bhh[R]); r.u[2]=0; r.u[3]=0; return r.s8; }
    if(g==3) return zero8();
    return g8(&Whh[R*16 + (g==2?8:0)]);
}
// head/folded-dec B-frag: [W(np) k<16 | bias@16 | 0]
__device__ __forceinline__ short8 gH(const float* __restrict__ W,const float* __restrict__ b,
                                     int np,int nvalid,int g){
    if(np>=nvalid || g==3) return zero8();
    if(g==2){ pk8 r; r.u[0]=(unsigned)f2bf(b[np]); r.u[1]=0;r.u[2]=0;r.u[3]=0; return r.s8; }
    return g8(&W[np*16 + (g==1?8:0)]);
}

struct XB { float2 q[4]; float2 t; };
__device__ __forceinline__ void ldrow(const float* __restrict__ obs,int t,int row,int g,XB&x){
    const float* p = obs + ((size_t)t*BATCH + row)*POSE;
    const float2* p2 = (const float2*)(p + 8*g);
    x.q[0]=p2[0]; x.q[1]=p2[1]; x.q[2]=p2[2]; x.q[3]=p2[3];
    x.t=*(const float2*)(p+32);
}
__device__ __forceinline__ short8 packx(const XB&x){
    pk8 r;
#pragma unroll
    for(int p=0;p<4;++p) r.u[p]=f22bf(x.q[p].x,x.q[p].y);
    return r.s8;
}
// A-frag [h16 | 1@16 | 0] (heads + folded dec)
__device__ __forceinline__ short8 afragH(const unsigned short (*hb)[40],int lo,int g){
    short8 h8=*(const short8*)&hb[lo][(g&1)?8:0];
    pk8 bf; bf.u[0]=0x3F80u; bf.u[1]=0;bf.u[2]=0;bf.u[3]=0;
    return (g>=2)?((g==2)?bf.s8:zero8()):h8;
}
// A-frag crossing folded: [p0,p1,1@2,0..| hc@8..24 | 0]
__device__ __forceinline__ short8 afragC(const unsigned short (*hb)[40],const float2* pb,int lo,int g){
    short8 h8=*(const short8*)&hb[lo][(g==2)?8:0];
    float2 p=pb[lo];
    pk8 pf; pf.u[0]=f22bf(p.x,p.y); pf.u[1]=0x3F80u; pf.u[2]=0; pf.u[3]=0;
    return (g==0)?pf.s8:((g==3)?zero8():h8);
}
// A-frag K64 chunk1: [x32,x33,1@34,0..| h@40..56 | 0]
__device__ __forceinline__ short8 afragE(const unsigned short (*hb)[40],unsigned xt,int lo,int g){
    short8 h8=*(const short8*)&hb[lo][(g==2)?8:0];
    pk8 xf; xf.u[0]=xt; xf.u[1]=0x3F80u; xf.u[2]=0; xf.u[3]=0;
    return (g==0)?xf.s8:((g==3)?zero8():h8);
}

extern "C" __global__ void __launch_bounds__(128,4) lstm_pair(
    const float* __restrict__ obs_s,
    const float* __restrict__ eWih, const float* __restrict__ eWhh,
    const float* __restrict__ ebih, const float* __restrict__ ebhh,
    const float* __restrict__ dWih, const float* __restrict__ dWhh,
    const float* __restrict__ dbih, const float* __restrict__ dbhh,
    const float* __restrict__ cWih, const float* __restrict__ cWhh,
    const float* __restrict__ cbih, const float* __restrict__ cbhh,
    const float* __restrict__ fcW,  const float* __restrict__ fcb,
    const float* __restrict__ fccW, const float* __restrict__ fccb,
    const float* __restrict__ mlpW, const float* __restrict__ mlpb,
    const float* __restrict__ embW, const float* __restrict__ embb,
    float* __restrict__ out_s, float* __restrict__ out_cr)
{
    __shared__ float exch[4][16][20];                       // 5120 B, aliased as fold
    __shared__ unsigned short hD[16][40];                   // 1280 B
    __shared__ unsigned short hC[16][40];                   // 1280 B
    __shared__ float2 pbuf[16];

    unsigned short (*fold)[16][40]=(unsigned short(*)[16][40])&exch[0][0][0];

    const int tid=threadIdx.x;
    const int l=tid&63, wv=tid>>6;
    const int lo=l&15, g=l>>4;
    const int gt0=2*wv;                    // this wave's gate tiles: gt0, gt0+1
    const int pb=blockIdx.x*16;
    const int d=8*wv+(l>>3);               // pointwise: dim owned
    const int b2=(l&7)*2;                  // pointwise: batch pair base
    const f32x4 z4={0.f,0.f,0.f,0.f};

    for(int idx=tid; idx<320; idx+=128){ ((unsigned*)hD)[idx]=0u; ((unsigned*)hC)[idx]=0u; }

    // encoder weights -> regs (per-lane gather)
    short8 wEa[2], wEb[2];
#pragma unroll
    for(int i=0;i<2;++i){
        int R=(gt0+i)*16+lo;
        wEa[i]=g8(&eWih[R*34+8*g]);
        wEb[i]=gW1(eWih,eWhh,ebih,ebhh,R,g);
    }
    __syncthreads();

    float cS[2]={0.f,0.f};   // enc/dec chain c (elements (d,b2),(d,b2+1))
    float cC[2]={0.f,0.f};   // crossing chain c

    auto pw_tail=[&](float (&cs)[2], unsigned short (*hb)[40]){
        float2 v[4];
#pragma unroll
        for(int gt=0;gt<4;++gt) v[gt]=*(const float2*)&exch[gt][d][b2];
        unsigned short hsh[2];
#pragma unroll
        for(int e=0;e<2;++e){
            float iv=sigm(e?v[0].y:v[0].x);
            float fv=sigm(e?v[1].y:v[1].x);
            float gv=tanh_(e?v[2].y:v[2].x);
            float ov=sigm(e?v[3].y:v[3].x);
            float cn=fmaf(fv,cs[e],iv*gv);
            cs[e]=cn;
            hsh[e]=f2bf(ov*tanh_(cn));
        }
        hb[b2][d]=hsh[0];
        hb[b2+1][d]=hsh[1];
    };

    // ---------------- encoder ----------------
    XB xA,xB_;
    ldrow(obs_s,0,pb+lo,g,xA);
    ldrow(obs_s,1,pb+lo,g,xB_);
    auto enc_one=[&](int t, XB& X){
        short8 a0=packx(X);
        unsigned xt=f22bf(X.t.x,X.t.y);
        short8 a1=afragE(hD,xt,lo,g);
        int tn=t+2; if(tn>SEQLEN-1) tn=SEQLEN-1;
        ldrow(obs_s,tn,pb+lo,g,X);
        f32x4 acc[2];
#pragma unroll
        for(int i=0;i<2;++i){
            f32x4 c0=MF(a0,wEa[i],z4);
            acc[i]=MF(a1,wEb[i],c0);
        }
#pragma unroll
        for(int i=0;i<2;++i) *(f32x4*)&exch[gt0+i][lo][4*g]=acc[i];
        __syncthreads();
        pw_tail(cS,hD);
        __syncthreads();
    };
    for(int tt=0;tt<16;++tt){ enc_one(2*tt,xA); enc_one(2*tt+1,xB_); }

    // ---------------- post-encoder staging ----------------
    // mlp: hc0 = mlpW.h + mlpb (wave1 computes, publishes to hC)
    if(wv==1){
        short8 wM=gH(mlpW,mlpb,lo,16,g);
        short8 a=afragH(hD,lo,g);
        f32x4 o=MF(a,wM,z4);
#pragma unroll
        for(int j=0;j<4;++j) hC[4*g+j][lo]=f2bf(o[j]);
    }
    // fold decoder: Wde[64][k] : k<16: dWhh + dWih.fcW ; k16: db + dWih.fcb
    for(int idx=tid; idx<2560; idx+=128){
        int k=idx%40, n=(idx/40)&15, gt=idx/640;
        int R=gt*16+n; float v=0.f;
        if(k<16){ v=dWhh[R*16+k];
            for(int p=0;p<34;++p) v=fmaf(dWih[R*34+p],fcW[p*16+k],v);
        } else if(k==16){ v=dbih[R]+dbhh[R];
            for(int p=0;p<34;++p) v=fmaf(dWih[R*34+p],fcb[p],v);
        }
        fold[gt][n][k]=f2bf(v);
    }
    __syncthreads();
    short8 wDe[2];
#pragma unroll
    for(int i=0;i<2;++i) wDe[i]=*(const short8*)&fold[gt0+i][lo][8*g];
    __syncthreads();
    // fold crossing: k0,k1: cWih.embW ; k2: cb + cWih.embb ; k8..23: cWhh
    for(int idx=tid; idx<2560; idx+=128){
        int k=idx%40, n=(idx/40)&15, gt=idx/640;
        int R=gt*16+n; float v=0.f;
        if(k<2){ for(int p=0;p<34;++p) v=fmaf(cWih[R*34+p],embW[2*p+k],v); }
        else if(k==2){ v=cbih[R]+cbhh[R];
            for(int p=0;p<34;++p) v=fmaf(cWih[R*34+p],embb[p],v); }
        else if(k>=8&&k<24){ v=cWhh[R*16+(k-8)]; }
        fold[gt][n][k]=f2bf(v);
    }
    __syncthreads();
    short8 wCp[2];
#pragma unroll
    for(int i=0;i<2;++i) wCp[i]=*(const short8*)&fold[gt0+i][lo][8*g];
    // head weights -> regs
    short8 wF[2], wFC=zero8();
    if(wv==0){ wF[0]=gH(fcW,fcb,lo,34,g); wF[1]=gH(fcW,fcb,16+lo,34,g); }
    else     { wF[0]=gH(fcW,fcb,32+lo,34,g); wF[1]=zero8(); wFC=gH(fccW,fccb,lo,2,g); }
    __syncthreads();

    auto fcc_soft=[&](int s){
        if(wv==1){
            short8 ac=afragH(hC,lo,g);
            f32x4 zz=MF(ac,wFC,z4);
            float zs[4];
#pragma unroll
            for(int j=0;j<4;++j) zs[j]=__shfl_xor(zz[j],1);
            if(lo==0){
#pragma unroll
                for(int j=0;j<4;++j){
                    float z0=zz[j], z1=zs[j];
                    float mx=fmaxf(z0,z1);
                    float e0=__expf(z0-mx), e1=__expf(z1-mx);
                    float rs=__builtin_amdgcn_rcpf(e0+e1);
                    float2 p=make_float2(e0*rs,e1*rs);
                    int b=4*g+j;
                    pbuf[b]=p;
                    *(float2*)&out_cr[((size_t)s*BATCH+pb+b)*2]=p;
                }
            }
        }
    };
    auto fc_out=[&](int s){
        short8 ah=afragH(hD,lo,g);
        if(wv==0){
#pragma unroll
            for(int nt=0;nt<2;++nt){
                f32x4 o=MF(ah,wF[nt],z4);
                int np=nt*16+lo;
#pragma unroll
                for(int j=0;j<4;++j)
                    out_s[((size_t)s*BATCH+pb+4*g+j)*POSE+np]=o[j];
            }
        } else {
            f32x4 o=MF(ah,wF[0],z4);
            int np=32+lo;
            if(np<POSE){
#pragma unroll
                for(int j=0;j<4;++j)
                    out_s[((size_t)s*BATCH+pb+4*g+j)*POSE+np]=o[j];
            }
        }
    };

    // ---------------- s = 0 (peeled: original K=64 weights) ----------------
    {
        short8 wC64a[2],wC64b[2],wD64a[2],wD64b[2];
#pragma unroll
        for(int i=0;i<2;++i){
            int R=(gt0+i)*16+lo;
            wC64a[i]=g8(&cWih[R*34+8*g]); wC64b[i]=gW1(cWih,cWhh,cbih,cbhh,R,g);
            wD64a[i]=g8(&dWih[R*34+8*g]); wD64b[i]=gW1(dWih,dWhh,dbih,dbhh,R,g);
        }
        XB xq; ldrow(obs_s,SEQLEN-1,pb+lo,g,xq);
        short8 a0q=packx(xq);
        unsigned xtq=f22bf(xq.t.x,xq.t.y);

        f32x4 acc[2];
        // crossing cell (inputs obs[-1], hc)
        short8 a1c=afragE(hC,xtq,lo,g);
#pragma unroll
        for(int i=0;i<2;++i){ f32x4 c0=MF(a0q,wC64a[i],z4); acc[i]=MF(a1c,wC64b[i],c0); }
#pragma unroll
        for(int i=0;i<2;++i) *(f32x4*)&exch[gt0+i][lo][4*g]=acc[i];
        __syncthreads();
        pw_tail(cC,hC);
        __syncthreads();
        // decoder cell (inputs obs[-1], h)
        short8 a1d=afragE(hD,xtq,lo,g);
#pragma unroll
        for(int i=0;i<2;++i){ f32x4 c0=MF(a0q,wD64a[i],z4); acc[i]=MF(a1d,wD64b[i],c0); }
#pragma unroll
        for(int i=0;i<2;++i) *(f32x4*)&exch[gt0+i][lo][4*g]=acc[i];
        fcc_soft(0);
        __syncthreads();
        pw_tail(cS,hD);
        __syncthreads();
        fc_out(0);
    }
    // ---------------- s = 1..14 (folded K=32, weights in VGPRs) ----------------
    for(int s=1;s<PREDL;++s){
        f32x4 acc[2];
        short8 ac=afragC(hC,pbuf,lo,g);
#pragma unroll
        for(int i=0;i<2;++i) acc[i]=MF(ac,wCp[i],z4);
#pragma unroll
        for(int i=0;i<2;++i) *(f32x4*)&exch[gt0+i][lo][4*g]=acc[i];
        __syncthreads();
        pw_tail(cC,hC);
        __syncthreads();
        short8 ad=afragH(hD,lo,g);
#pragma unroll
        for(int i=0;i<2;++i) acc[i]=MF(ad,wDe[i],z4);
#pragma unroll
        for(int i=0;i<2;++i) *(f32x4*)&exch[gt0+i][lo][4*g]=acc[i];
        fcc_soft(s);
        __syncthreads();
        pw_tail(cS,hD);
        __syncthreads();
        fc_out(s);
    }
}

extern "C" void kernel_launch(void* const* d_in, const int* in_sizes, int n_in,
                              void* d_out, int out_size, void* d_ws, size_t ws_size,
                              hipStream_t stream)
{
    const float* obs  = (const float*)d_in[0];
    const float* eWih = (const float*)d_in[1];
    const float* eWhh = (const float*)d_in[2];
    const float* ebih = (const float*)d_in[3];
    const float* ebhh = (const float*)d_in[4];
    const float* dWih = (const float*)d_in[5];
    const float* dWhh = (const float*)d_in[6];
    const float* dbih = (const float*)d_in[7];
    const float* dbhh = (const float*)d_in[8];
    const float* cWih = (const float*)d_in[9];
    const float* cWhh = (const float*)d_in[10];
    const float* cbih = (const float*)d_in[11];
    const float* cbhh = (const float*)d_in[12];
    const float* fcW  = (const float*)d_in[13];
    const float* fcb  = (const float*)d_in[14];
    const float* fccW = (const float*)d_in[15];
    const float* fccb = (const float*)d_in[16];
    const float* mlpW = (const float*)d_in[17];
    const float* mlpb = (const float*)d_in[18];
    const float* embW = (const float*)d_in[19];
    const float* embb = (const float*)d_in[20];

    float* out_s  = (float*)d_out;
    float* out_cr = out_s + (size_t)PREDL*BATCH*POSE;

    dim3 grid(BATCH/16), block(128);
    hipLaunchKernelGGL(lstm_pair, grid, block, 0, stream,
                       obs, eWih, eWhh, ebih, ebhh, dWih, dWhh, dbih, dbhh,
                       cWih, cWhh, cbih, cbhh, fcW, fcb, fccW, fccb,
                       mlpW, mlpb, embW, embb, out_s, out_cr);
}

// Round 6
// 102.920 us; speedup vs baseline: 2.3539x; 2.3539x over previous
//
#include <hip/hip_runtime.h>
#include <cstddef>

#define SEQLEN 32
#define BATCH  32768
#define POSE   34
#define PREDL  15

typedef __attribute__((ext_vector_type(8))) short short8;
typedef __attribute__((ext_vector_type(4))) float f32x4;
typedef union { short8 s8; unsigned u[4]; } pk8;

#define MF(a,b,c) __builtin_amdgcn_mfma_f32_16x16x32_bf16(a,b,c,0,0,0)

__device__ __forceinline__ float sigm(float x){ return __builtin_amdgcn_rcpf(1.0f+__expf(-x)); }
__device__ __forceinline__ float tanh_(float x){ return fmaf(2.0f, __builtin_amdgcn_rcpf(1.0f+__expf(-2.0f*x)), -1.0f); }
__device__ __forceinline__ unsigned short f2bf(float f){ __bf16 b=(__bf16)f; return __builtin_bit_cast(unsigned short,b); }
__device__ __forceinline__ unsigned f22bf(float lo,float hi){ return (unsigned)f2bf(lo) | ((unsigned)f2bf(hi)<<16); }
__device__ __forceinline__ short8 zero8(){ pk8 r; r.u[0]=0;r.u[1]=0;r.u[2]=0;r.u[3]=0; return r.s8; }

// 8 consecutive global floats -> bf16x8 (one-time weight gathers)
__device__ __forceinline__ short8 g8(const float* __restrict__ p){
    pk8 r;
    float2 q0=*(const float2*)p, q1=*(const float2*)(p+2);
    float2 q2=*(const float2*)(p+4), q3=*(const float2*)(p+6);
    r.u[0]=f22bf(q0.x,q0.y); r.u[1]=f22bf(q1.x,q1.y);
    r.u[2]=f22bf(q2.x,q2.y); r.u[3]=f22bf(q3.x,q3.y);
    return r.s8;
}
// A-frag chunk1 of K64 weights: g0=[W32,W33,bias,0..] g1=Whh[0..8) g2=Whh[8..16) g3=0
__device__ __forceinline__ short8 gW1(const float* __restrict__ Wih,const float* __restrict__ Whh,
                                      const float* __restrict__ bih,const float* __restrict__ bhh,
                                      int R,int g){
    if(g==0){ pk8 r; r.u[0]=f22bf(Wih[R*34+32],Wih[R*34+33]);
              r.u[1]=(unsigned)f2bf(bih[R]+bhh[R]); r.u[2]=0; r.u[3]=0; return r.s8; }
    if(g==3) return zero8();
    return g8(&Whh[R*16 + (g==2?8:0)]);
}
// head A-frag: [W(np)[0..16) | bias@16 | 0]
__device__ __forceinline__ short8 gH(const float* __restrict__ W,const float* __restrict__ b,
                                     int np,int nvalid,int g){
    if(np>=nvalid || g==3) return zero8();
    if(g==2){ pk8 r; r.u[0]=(unsigned)f2bf(b[np]); r.u[1]=0;r.u[2]=0;r.u[3]=0; return r.s8; }
    return g8(&W[np*16 + (g==1?8:0)]);
}

// ---- B-frag builders: col = lane&15 = batch, k = 8*(lane>>4)+e ----
// K64 chunk1 (x32,x33,bias@34, h@40..56) OR folded-cross K32 (p0,p1,bias@2, hc@8..24)
__device__ __forceinline__ short8 mk_b1(unsigned hp0,unsigned hp1,int lo,int g,unsigned u0g0){
    int sA=(lo+32*(g-1))&63, sB=(sA+16)&63;
    unsigned a=__shfl(hp0,sA,64), b=__shfl(hp1,sA,64);
    unsigned c=__shfl(hp0,sB,64), d=__shfl(hp1,sB,64);
    bool mid=(g==1)||(g==2);
    pk8 r;
    r.u[0]=(g==0)?u0g0:(mid?a:0u);
    r.u[1]=(g==0)?0x3F80u:(mid?b:0u);
    r.u[2]=mid?c:0u; r.u[3]=mid?d:0u;
    return r.s8;
}
// head/folded-dec K32: [h@0..16 | bias@16 | 0]
__device__ __forceinline__ short8 mk_bh(unsigned hp0,unsigned hp1,int lo,int g){
    int sA=(lo+32*g)&63, sB=(sA+16)&63;
    unsigned a=__shfl(hp0,sA,64), b=__shfl(hp1,sA,64);
    unsigned c=__shfl(hp0,sB,64), d=__shfl(hp1,sB,64);
    bool lowg=(g<2);
    pk8 r;
    r.u[0]=lowg?a:(g==2?0x3F80u:0u);
    r.u[1]=lowg?b:0u; r.u[2]=lowg?c:0u; r.u[3]=lowg?d:0u;
    return r.s8;
}

struct XB { float2 q[4]; float2 t; };
__device__ __forceinline__ void ldrow(const float* __restrict__ obs,int t,int row,int g,XB&x){
    const float* p = obs + ((size_t)t*BATCH + row)*POSE;
    const float2* p2 = (const float2*)(p + 8*g);
    x.q[0]=p2[0]; x.q[1]=p2[1]; x.q[2]=p2[2]; x.q[3]=p2[3];
    x.t=*(const float2*)(p+32);
}
__device__ __forceinline__ short8 packx(const XB&x){
    pk8 r;
#pragma unroll
    for(int p=0;p<4;++p) r.u[p]=f22bf(x.q[p].x,x.q[p].y);
    return r.s8;
}
// pointwise: lane owns gate dims 4g+j (j=0..3) of its batch; c fp32-resident
__device__ __forceinline__ void pw(const f32x4 acc[4], float (&cs)[4], unsigned &hp0, unsigned &hp1){
    float hv[4];
#pragma unroll
    for(int j=0;j<4;++j){
        float iv=sigm(acc[0][j]);
        float fv=sigm(acc[1][j]);
        float gv=tanh_(acc[2][j]);
        float ov=sigm(acc[3][j]);
        float cn=fmaf(fv,cs[j],iv*gv);
        cs[j]=cn;
        hv[j]=ov*tanh_(cn);
    }
    hp0=f22bf(hv[0],hv[1]); hp1=f22bf(hv[2],hv[3]);
}

extern "C" __global__ void __launch_bounds__(256,2) lstm_w(
    const float* __restrict__ obs_s,
    const float* __restrict__ eWih, const float* __restrict__ eWhh,
    const float* __restrict__ ebih, const float* __restrict__ ebhh,
    const float* __restrict__ dWih, const float* __restrict__ dWhh,
    const float* __restrict__ dbih, const float* __restrict__ dbhh,
    const float* __restrict__ cWih, const float* __restrict__ cWhh,
    const float* __restrict__ cbih, const float* __restrict__ cbhh,
    const float* __restrict__ fcW,  const float* __restrict__ fcb,
    const float* __restrict__ fccW, const float* __restrict__ fccb,
    const float* __restrict__ mlpW, const float* __restrict__ mlpb,
    const float* __restrict__ embW, const float* __restrict__ embb,
    float* __restrict__ out_s, float* __restrict__ out_cr)
{
    __shared__ unsigned short foldD[4][16][40];   // folded decoder weights
    __shared__ unsigned short foldC[4][16][40];   // folded crossing weights

    const int tid=threadIdx.x;
    const int l=tid&63;
    const int wv=tid>>6;
    const int lo=l&15, g=l>>4;
    const int pb=blockIdx.x*64 + wv*16;           // this wave's batch base
    const f32x4 z4={0.f,0.f,0.f,0.f};

    // ---- one-time: fold decoder & crossing weights (exact f32, one bf16 round) ----
    for(int idx=tid; idx<2048; idx+=256){
        int k=idx&31, n=(idx>>5)&15, gt=idx>>9;
        int R=gt*16+n;
        float vD=0.f, vC=0.f;
        if(k<16){ vD=dWhh[R*16+k];
            for(int p=0;p<34;++p) vD=fmaf(dWih[R*34+p],fcW[p*16+k],vD); }
        else if(k==16){ vD=dbih[R]+dbhh[R];
            for(int p=0;p<34;++p) vD=fmaf(dWih[R*34+p],fcb[p],vD); }
        if(k<2){ for(int p=0;p<34;++p) vC=fmaf(cWih[R*34+p],embW[2*p+k],vC); }
        else if(k==2){ vC=cbih[R]+cbhh[R];
            for(int p=0;p<34;++p) vC=fmaf(cWih[R*34+p],embb[p],vC); }
        else if(k>=8&&k<24){ vC=cWhh[R*16+(k-8)]; }
        foldD[gt][n][k]=f2bf(vD);
        foldC[gt][n][k]=f2bf(vC);
    }

    // encoder weight A-frags (per-lane global gather; one-time)
    short8 wEa[4], wEb[4];
#pragma unroll
    for(int ti=0;ti<4;++ti){
        int R=ti*16+lo;
        wEa[ti]=g8(&eWih[R*34+8*g]);
        wEb[ti]=gW1(eWih,eWhh,ebih,ebhh,R,g);
    }
    // head A-frags
    short8 wFc[3], wMl, wFCc;
#pragma unroll
    for(int nt=0;nt<3;++nt) wFc[nt]=gH(fcW,fcb,nt*16+lo,34,g);
    wMl =gH(mlpW,mlpb,lo,16,g);
    wFCc=gH(fccW,fccb,lo,2,g);

    __syncthreads();
    short8 wDe[4], wCp[4];
#pragma unroll
    for(int ti=0;ti<4;++ti){
        wDe[ti]=*(const short8*)&foldD[ti][lo][8*g];
        wCp[ti]=*(const short8*)&foldC[ti][lo][8*g];
    }
    // no further barriers: waves fully independent

    // ---- encoder: 32 steps, depth-2 reg prefetch, all-reg recurrence ----
    float cS[4]={0.f,0.f,0.f,0.f};
    unsigned hp0=0u, hp1=0u;
    XB xA,xB_;
    ldrow(obs_s,0,pb+lo,g,xA);
    ldrow(obs_s,1,pb+lo,g,xB_);

    auto enc_one=[&](int t, XB &X){
        short8 b0=packx(X);
        unsigned xt=f22bf(X.t.x,X.t.y);
        short8 b1=mk_b1(hp0,hp1,lo,g,xt);
        int tn=t+2; if(tn>SEQLEN-1) tn=SEQLEN-1;
        ldrow(obs_s,tn,pb+lo,g,X);
        f32x4 acc[4];
#pragma unroll
        for(int ti=0;ti<4;++ti){
            f32x4 c0=MF(wEa[ti],b0,z4);
            acc[ti]=MF(wEb[ti],b1,c0);
        }
        pw(acc,cS,hp0,hp1);
    };
    for(int tt=0;tt<16;++tt){ enc_one(2*tt,xA); enc_one(2*tt+1,xB_); }
    // xA now holds obs[31]

    // ---- hc = mlp(h_enc) + mlpb : lands in pointwise ownership layout directly ----
    unsigned hcp0,hcp1;
    {
        short8 bhE=mk_bh(hp0,hp1,lo,g);
        f32x4 o=MF(wMl,bhE,z4);
        hcp0=f22bf(o[0],o[1]); hcp1=f22bf(o[2],o[3]);
    }
    float cC[4]={0.f,0.f,0.f,0.f};
    unsigned pp=0u;
    short8 bH;   // dec-cell B-frag, carried across steps

    // shared decoder tail: fcc+softmax+out_cr, h->bH, fc head -> out_s
    auto dec_tail=[&](int s, const f32x4 (&aC)[4], const f32x4 (&aD)[4]){
        pw(aC,cC,hcp0,hcp1);
        pw(aD,cS,hp0,hp1);
        // fcc on new hc: z0,z1 in rows 0,1 -> lanes g==0, j=0,1
        short8 bHC=mk_bh(hcp0,hcp1,lo,g);
        f32x4 zz=MF(wFCc,bHC,z4);
        float z0=zz[0], z1=zz[1];
        float mx=fmaxf(z0,z1);
        float e0=__expf(z0-mx), e1=__expf(z1-mx);
        float rs=__builtin_amdgcn_rcpf(e0+e1);
        float p0=e0*rs, p1=e1*rs;
        pp=f22bf(p0,p1);                        // only g==0 lanes' value is consumed
        if(g==0)
            ((float2*)out_cr)[(size_t)s*BATCH+pb+lo]=make_float2(p0,p1);
        // new dec B-frag (also fc-head B operand)
        bH=mk_bh(hp0,hp1,lo,g);
        // fc head: D[out-dim][batch]; lane stores 4 contiguous dims of batch lo
        float* po = out_s + ((size_t)s*BATCH + pb + lo)*POSE;
        f32x4 o0=MF(wFc[0],bH,z4);
        f32x4 o1=MF(wFc[1],bH,z4);
        *(float2*)(po+4*g)   =make_float2(o0[0],o0[1]);
        *(float2*)(po+4*g+2) =make_float2(o0[2],o0[3]);
        *(float2*)(po+16+4*g)  =make_float2(o1[0],o1[1]);
        *(float2*)(po+16+4*g+2)=make_float2(o1[2],o1[3]);
        f32x4 o2=MF(wFc[2],bH,z4);
        if(g==0) *(float2*)(po+32)=make_float2(o2[0],o2[1]);
    };

    // ---- s=0 (peeled: original K=64 weights, inputs obs[31]) ----
    {
        short8 b0=packx(xA);
        unsigned xt=f22bf(xA.t.x,xA.t.y);
        f32x4 aC[4], aD[4];
        {
            short8 wa[4], wb[4];
#pragma unroll
            for(int ti=0;ti<4;++ti){
                int R=ti*16+lo;
                wa[ti]=g8(&cWih[R*34+8*g]);
                wb[ti]=gW1(cWih,cWhh,cbih,cbhh,R,g);
            }
            short8 b1=mk_b1(hcp0,hcp1,lo,g,xt);
#pragma unroll
            for(int ti=0;ti<4;++ti){
                f32x4 c0=MF(wa[ti],b0,z4);
                aC[ti]=MF(wb[ti],b1,c0);
            }
        }
        {
            short8 wa[4], wb[4];
#pragma unroll
            for(int ti=0;ti<4;++ti){
                int R=ti*16+lo;
                wa[ti]=g8(&dWih[R*34+8*g]);
                wb[ti]=gW1(dWih,dWhh,dbih,dbhh,R,g);
            }
            short8 b1=mk_b1(hp0,hp1,lo,g,xt);
#pragma unroll
            for(int ti=0;ti<4;++ti){
                f32x4 c0=MF(wa[ti],b0,z4);
                aD[ti]=MF(wb[ti],b1,c0);
            }
        }
        dec_tail(0,aC,aD);
    }
    // ---- s=1..14: folded K=32 cells, zero LDS, zero barriers ----
    for(int s=1;s<PREDL;++s){
        short8 bC=mk_b1(hcp0,hcp1,lo,g,pp);
        f32x4 aC[4], aD[4];
#pragma unroll
        for(int ti=0;ti<4;++ti) aD[ti]=MF(wDe[ti],bH,z4);
#pragma unroll
        for(int ti=0;ti<4;++ti) aC[ti]=MF(wCp[ti],bC,z4);
        dec_tail(s,aC,aD);
    }
}

extern "C" void kernel_launch(void* const* d_in, const int* in_sizes, int n_in,
                              void* d_out, int out_size, void* d_ws, size_t ws_size,
                              hipStream_t stream)
{
    const float* obs  = (const float*)d_in[0];
    const float* eWih = (const float*)d_in[1];
    const float* eWhh = (const float*)d_in[2];
    const float* ebih = (const float*)d_in[3];
    const float* ebhh = (const float*)d_in[4];
    const float* dWih = (const float*)d_in[5];
    const float* dWhh = (const float*)d_in[6];
    const float* dbih = (const float*)d_in[7];
    const float* dbhh = (const float*)d_in[8];
    const float* cWih = (const float*)d_in[9];
    const float* cWhh = (const float*)d_in[10];
    const float* cbih = (const float*)d_in[11];
    const float* cbhh = (const float*)d_in[12];
    const float* fcW  = (const float*)d_in[13];
    const float* fcb  = (const float*)d_in[14];
    const float* fccW = (const float*)d_in[15];
    const float* fccb = (const float*)d_in[16];
    const float* mlpW = (const float*)d_in[17];
    const float* mlpb = (const float*)d_in[18];
    const float* embW = (const float*)d_in[19];
    const float* embb = (const float*)d_in[20];

    float* out_s  = (float*)d_out;
    float* out_cr = out_s + (size_t)PREDL*BATCH*POSE;

    dim3 grid(BATCH/64), block(256);
    hipLaunchKernelGGL(lstm_w, grid, block, 0, stream,
                       obs, eWih, eWhh, ebih, ebhh, dWih, dWhh, dbih, dbhh,
                       cWih, cWhh, cbih, cbhh, fcW, fcb, fccW, fccb,
                       mlpW, mlpb, embW, embb, out_s, out_cr);
}

// Round 7
// 102.239 us; speedup vs baseline: 2.3696x; 1.0067x over previous
//
#include <hip/hip_runtime.h>
#include <cstddef>

#define SEQLEN 32
#define BATCH  32768
#define POSE   34
#define PREDL  15

typedef __attribute__((ext_vector_type(8))) short short8;
typedef __attribute__((ext_vector_type(4))) float f32x4;
typedef union { short8 s8; unsigned u[4]; } pk8;

#define MF(a,b,c) __builtin_amdgcn_mfma_f32_16x16x32_bf16(a,b,c,0,0,0)

__device__ __forceinline__ float sigm(float x){ return __builtin_amdgcn_rcpf(1.0f+__expf(-x)); }
__device__ __forceinline__ float tanh_(float x){ return fmaf(2.0f, __builtin_amdgcn_rcpf(1.0f+__expf(-2.0f*x)), -1.0f); }
__device__ __forceinline__ unsigned short f2bf(float f){ __bf16 b=(__bf16)f; return __builtin_bit_cast(unsigned short,b); }
__device__ __forceinline__ unsigned f22bf(float lo,float hi){ return (unsigned)f2bf(lo) | ((unsigned)f2bf(hi)<<16); }
__device__ __forceinline__ short8 zero8(){ pk8 r; r.u[0]=0;r.u[1]=0;r.u[2]=0;r.u[3]=0; return r.s8; }

// 8 consecutive global floats -> bf16x8 (one-time weight gathers)
__device__ __forceinline__ short8 g8(const float* __restrict__ p){
    pk8 r;
    float2 q0=*(const float2*)p, q1=*(const float2*)(p+2);
    float2 q2=*(const float2*)(p+4), q3=*(const float2*)(p+6);
    r.u[0]=f22bf(q0.x,q0.y); r.u[1]=f22bf(q1.x,q1.y);
    r.u[2]=f22bf(q2.x,q2.y); r.u[3]=f22bf(q3.x,q3.y);
    return r.s8;
}
// A-frag chunk1 of K64 weights: g0=[W32,W33,bias,0..] g1=Whh[0..8) g2=Whh[8..16) g3=0
__device__ __forceinline__ short8 gW1(const float* __restrict__ Wih,const float* __restrict__ Whh,
                                      const float* __restrict__ bih,const float* __restrict__ bhh,
                                      int R,int g){
    if(g==0){ pk8 r; r.u[0]=f22bf(Wih[R*34+32],Wih[R*34+33]);
              r.u[1]=(unsigned)f2bf(bih[R]+bhh[R]); r.u[2]=0; r.u[3]=0; return r.s8; }
    if(g==3) return zero8();
    return g8(&Whh[R*16 + (g==2?8:0)]);
}
// head A-frag: [W(np)[0..16) | bias@16 | 0]
__device__ __forceinline__ short8 gH(const float* __restrict__ W,const float* __restrict__ b,
                                     int np,int nvalid,int g){
    if(np>=nvalid || g==3) return zero8();
    if(g==2){ pk8 r; r.u[0]=(unsigned)f2bf(b[np]); r.u[1]=0;r.u[2]=0;r.u[3]=0; return r.s8; }
    return g8(&W[np*16 + (g==1?8:0)]);
}

// ---- B-frag builders: col = lane&15 = batch, k = 8*(lane>>4)+e ----
__device__ __forceinline__ short8 mk_b1(unsigned hp0,unsigned hp1,int lo,int g,unsigned u0g0){
    int sA=(lo+32*(g-1))&63, sB=(sA+16)&63;
    unsigned a=__shfl(hp0,sA,64), b=__shfl(hp1,sA,64);
    unsigned c=__shfl(hp0,sB,64), d=__shfl(hp1,sB,64);
    bool mid=(g==1)||(g==2);
    pk8 r;
    r.u[0]=(g==0)?u0g0:(mid?a:0u);
    r.u[1]=(g==0)?0x3F80u:(mid?b:0u);
    r.u[2]=mid?c:0u; r.u[3]=mid?d:0u;
    return r.s8;
}
__device__ __forceinline__ short8 mk_bh(unsigned hp0,unsigned hp1,int lo,int g){
    int sA=(lo+32*g)&63, sB=(sA+16)&63;
    unsigned a=__shfl(hp0,sA,64), b=__shfl(hp1,sA,64);
    unsigned c=__shfl(hp0,sB,64), d=__shfl(hp1,sB,64);
    bool lowg=(g<2);
    pk8 r;
    r.u[0]=lowg?a:(g==2?0x3F80u:0u);
    r.u[1]=lowg?b:0u; r.u[2]=lowg?c:0u; r.u[3]=lowg?d:0u;
    return r.s8;
}
// pointwise: lane owns gate dims 4g+j of its batch; c fp32-resident
__device__ __forceinline__ void pw(const f32x4 acc[4], float (&cs)[4], unsigned &hp0, unsigned &hp1){
    float hv[4];
#pragma unroll
    for(int j=0;j<4;++j){
        float iv=sigm(acc[0][j]);
        float fv=sigm(acc[1][j]);
        float gv=tanh_(acc[2][j]);
        float ov=sigm(acc[3][j]);
        float cn=fmaf(fv,cs[j],iv*gv);
        cs[j]=cn;
        hv[j]=ov*tanh_(cn);
    }
    hp0=f22bf(hv[0],hv[1]); hp1=f22bf(hv[2],hv[3]);
}

// ---- prep kernel: fold decoder & crossing weights once into workspace ----
extern "C" __global__ void lstm_prep(
    const float* __restrict__ dWih, const float* __restrict__ dWhh,
    const float* __restrict__ dbih, const float* __restrict__ dbhh,
    const float* __restrict__ cWih, const float* __restrict__ cWhh,
    const float* __restrict__ cbih, const float* __restrict__ cbhh,
    const float* __restrict__ fcW,  const float* __restrict__ fcb,
    const float* __restrict__ embW, const float* __restrict__ embb,
    unsigned short* __restrict__ wsD, unsigned short* __restrict__ wsC)
{
    for(int idx=threadIdx.x; idx<2048; idx+=256){
        int k=idx&31, n=(idx>>5)&15, gt=idx>>9;
        int R=gt*16+n;
        float vD=0.f, vC=0.f;
        if(k<16){ vD=dWhh[R*16+k];
            for(int p=0;p<34;++p) vD=fmaf(dWih[R*34+p],fcW[p*16+k],vD); }
        else if(k==16){ vD=dbih[R]+dbhh[R];
            for(int p=0;p<34;++p) vD=fmaf(dWih[R*34+p],fcb[p],vD); }
        if(k<2){ for(int p=0;p<34;++p) vC=fmaf(cWih[R*34+p],embW[2*p+k],vC); }
        else if(k==2){ vC=cbih[R]+cbhh[R];
            for(int p=0;p<34;++p) vC=fmaf(cWih[R*34+p],embb[p],vC); }
        else if(k>=8&&k<24) vC=cWhh[R*16+(k-8)];
        wsD[idx]=f2bf(vD); wsC[idx]=f2bf(vC);
    }
}

extern "C" __global__ void __launch_bounds__(256,2) lstm_w2(
    const float* __restrict__ obs_s,
    const float* __restrict__ eWih, const float* __restrict__ eWhh,
    const float* __restrict__ ebih, const float* __restrict__ ebhh,
    const float* __restrict__ dWih, const float* __restrict__ dWhh,
    const float* __restrict__ dbih, const float* __restrict__ dbhh,
    const float* __restrict__ cWih, const float* __restrict__ cWhh,
    const float* __restrict__ cbih, const float* __restrict__ cbhh,
    const float* __restrict__ fcW,  const float* __restrict__ fcb,
    const float* __restrict__ fccW, const float* __restrict__ fccb,
    const float* __restrict__ mlpW, const float* __restrict__ mlpb,
    const unsigned short* __restrict__ wsD, const unsigned short* __restrict__ wsC,
    float* __restrict__ out_s, float* __restrict__ out_cr)
{
    __shared__ unsigned xt[4][2][320];   // per-wave double-buffered x tile (16 rows x 20 words)

    const int tid=threadIdx.x;
    const int l=tid&63;
    const int wv=tid>>6;
    const int lo=l&15, g=l>>4;
    const int pb=blockIdx.x*64 + wv*16;
    const f32x4 z4={0.f,0.f,0.f,0.f};
    unsigned* XT0=&xt[wv][0][0];
    unsigned* XT1=&xt[wv][1][0];

    // staging index precompute: flat pair idx i2 = l + 64*it ; row=i2/17, w=i2%17
    unsigned pofs[5]; int wofs[5];
#pragma unroll
    for(int it=0; it<5; ++it){
        int i2=l+64*it;
        int r=i2/17, w=i2-r*17;
        pofs[it]=(unsigned)((pb+r)*17+w);
        wofs[it]=r*20+w;
    }

    // encoder weight A-frags (one-time gathers)
    short8 wEa[4], wEb[4];
#pragma unroll
    for(int ti=0;ti<4;++ti){
        int R=ti*16+lo;
        wEa[ti]=g8(&eWih[R*34+8*g]);
        wEb[ti]=gW1(eWih,eWhh,ebih,ebhh,R,g);
    }

    float cS[4]={0.f,0.f,0.f,0.f};
    unsigned hp0=0u, hp1=0u;
    float2 sA[5],sB[5],sC[5];
    short8 fb; unsigned ft;

    auto ldset=[&](float2 (&S)[5], int t){
        const float2* base=(const float2*)obs_s + (size_t)t*(BATCH*17);
#pragma unroll
        for(int it=0;it<5;++it)
            if(it<4 || l<16) S[it]=base[pofs[it]];
    };
    auto wrset=[&](const float2 (&S)[5], unsigned* B){
#pragma unroll
        for(int it=0;it<5;++it)
            if(it<4 || l<16) B[wofs[it]]=f22bf(S[it].x,S[it].y);
    };
    auto rdfrag=[&](const unsigned* B, short8 &b, unsigned &tw){
        b=*(const short8*)&B[lo*20+4*g];
        tw=B[lo*20+16];
    };
    auto enc_compute=[&](short8 b0, unsigned tail){
        short8 b1=mk_b1(hp0,hp1,lo,g,tail);
        f32x4 acc[4];
#pragma unroll
        for(int ti=0;ti<4;++ti){
            f32x4 c0=MF(wEa[ti],b0,z4);
            acc[ti]=MF(wEb[ti],b1,c0);
        }
        pw(acc,cS,hp0,hp1);
    };

    // ---- encoder: depth-3 reg prefetch, frag read one step early, no barriers ----
    ldset(sA,0); ldset(sB,1); ldset(sC,2);
    wrset(sA,XT0);
    rdfrag(XT0,fb,ft);
    for(int k=0;k<10;++k){
        int t=3*k;
        short8 nfb; unsigned nft;
        // step t : write t+1, load t+3 -> sA
        if(t+3<=31) ldset(sA,t+3);
        { unsigned* Bn=(t&1)?XT0:XT1; wrset(sB,Bn); rdfrag(Bn,nfb,nft); }
        enc_compute(fb,ft); fb=nfb; ft=nft;
        // step t+1 : write t+2, load t+4 -> sB
        if(t+4<=31) ldset(sB,t+4);
        { unsigned* Bn=(t&1)?XT1:XT0; wrset(sC,Bn); rdfrag(Bn,nfb,nft); }
        enc_compute(fb,ft); fb=nfb; ft=nft;
        // step t+2 : write t+3, load t+5 -> sC
        if(t+5<=31) ldset(sC,t+5);
        { unsigned* Bn=(t&1)?XT0:XT1; wrset(sA,Bn); rdfrag(Bn,nfb,nft); }
        enc_compute(fb,ft); fb=nfb; ft=nft;
    }
    {   // step 30: write 31 (sB), prefetch frag 31
        short8 nfb; unsigned nft;
        wrset(sB,XT1); rdfrag(XT1,nfb,nft);
        enc_compute(fb,ft); fb=nfb; ft=nft;
    }
    enc_compute(fb,ft);     // step 31 ; fb/ft keep x(31) fragment for s0 peel

    // ---- decoder weights -> VGPRs ----
    short8 wDe[4], wCp[4];
#pragma unroll
    for(int ti=0;ti<4;++ti){
        wDe[ti]=*(const short8*)&wsD[(ti*16+lo)*32+8*g];
        wCp[ti]=*(const short8*)&wsC[(ti*16+lo)*32+8*g];
    }
    short8 wFc[3], wMl, wFCc;
#pragma unroll
    for(int nt=0;nt<3;++nt) wFc[nt]=gH(fcW,fcb,nt*16+lo,34,g);
    wMl =gH(mlpW,mlpb,lo,16,g);
    wFCc=gH(fccW,fccb,lo,2,g);

    // hc = mlp(h_enc)
    unsigned hcp0,hcp1;
    {
        short8 bhE=mk_bh(hp0,hp1,lo,g);
        f32x4 o=MF(wMl,bhE,z4);
        hcp0=f22bf(o[0],o[1]); hcp1=f22bf(o[2],o[3]);
    }
    float cC[4]={0.f,0.f,0.f,0.f};
    unsigned pp=0u;
    short8 bH;

    auto dec_tail=[&](int s, const f32x4 (&aC)[4], const f32x4 (&aD)[4]){
        pw(aC,cC,hcp0,hcp1);
        pw(aD,cS,hp0,hp1);
        short8 bHC=mk_bh(hcp0,hcp1,lo,g);
        f32x4 zz=MF(wFCc,bHC,z4);
        float z0=zz[0], z1=zz[1];
        float mx=fmaxf(z0,z1);
        float e0=__expf(z0-mx), e1=__expf(z1-mx);
        float rs=__builtin_amdgcn_rcpf(e0+e1);
        float p0=e0*rs, p1=e1*rs;
        pp=f22bf(p0,p1);
        if(g==0)
            ((float2*)out_cr)[(size_t)s*BATCH+pb+lo]=make_float2(p0,p1);
        bH=mk_bh(hp0,hp1,lo,g);
        float* po = out_s + ((size_t)s*BATCH + pb + lo)*POSE;
        f32x4 o0=MF(wFc[0],bH,z4);
        f32x4 o1=MF(wFc[1],bH,z4);
        *(float2*)(po+4*g)   =make_float2(o0[0],o0[1]);
        *(float2*)(po+4*g+2) =make_float2(o0[2],o0[3]);
        *(float2*)(po+16+4*g)  =make_float2(o1[0],o1[1]);
        *(float2*)(po+16+4*g+2)=make_float2(o1[2],o1[3]);
        f32x4 o2=MF(wFc[2],bH,z4);
        if(g==0) *(float2*)(po+32)=make_float2(o2[0],o2[1]);
    };

    // ---- s=0 (peeled: original K=64 weights, inputs = obs[31] from fb/ft) ----
    {
        f32x4 aC[4], aD[4];
        {
            short8 wa[4], wb[4];
#pragma unroll
            for(int ti=0;ti<4;++ti){
                int R=ti*16+lo;
                wa[ti]=g8(&cWih[R*34+8*g]);
                wb[ti]=gW1(cWih,cWhh,cbih,cbhh,R,g);
            }
            short8 b1=mk_b1(hcp0,hcp1,lo,g,ft);
#pragma unroll
            for(int ti=0;ti<4;++ti){
                f32x4 c0=MF(wa[ti],fb,z4);
                aC[ti]=MF(wb[ti],b1,c0);
            }
        }
        {
            short8 wa[4], wb[4];
#pragma unroll
            for(int ti=0;ti<4;++ti){
                int R=ti*16+lo;
                wa[ti]=g8(&dWih[R*34+8*g]);
                wb[ti]=gW1(dWih,dWhh,dbih,dbhh,R,g);
            }
            short8 b1=mk_b1(hp0,hp1,lo,g,ft);
#pragma unroll
            for(int ti=0;ti<4;++ti){
                f32x4 c0=MF(wa[ti],fb,z4);
                aD[ti]=MF(wb[ti],b1,c0);
            }
        }
        dec_tail(0,aC,aD);
    }
    // ---- s=1..14 : folded K=32 cells, zero LDS, zero barriers ----
    for(int s=1;s<PREDL;++s){
        short8 bC=mk_b1(hcp0,hcp1,lo,g,pp);
        f32x4 aC[4], aD[4];
#pragma unroll
        for(int ti=0;ti<4;++ti) aD[ti]=MF(wDe[ti],bH,z4);
#pragma unroll
        for(int ti=0;ti<4;++ti) aC[ti]=MF(wCp[ti],bC,z4);
        dec_tail(s,aC,aD);
    }
}

extern "C" void kernel_launch(void* const* d_in, const int* in_sizes, int n_in,
                              void* d_out, int out_size, void* d_ws, size_t ws_size,
                              hipStream_t stream)
{
    const float* obs  = (const float*)d_in[0];
    const float* eWih = (const float*)d_in[1];
    const float* eWhh = (const float*)d_in[2];
    const float* ebih = (const float*)d_in[3];
    const float* ebhh = (const float*)d_in[4];
    const float* dWih = (const float*)d_in[5];
    const float* dWhh = (const float*)d_in[6];
    const float* dbih = (const float*)d_in[7];
    const float* dbhh = (const float*)d_in[8];
    const float* cWih = (const float*)d_in[9];
    const float* cWhh = (const float*)d_in[10];
    const float* cbih = (const float*)d_in[11];
    const float* cbhh = (const float*)d_in[12];
    const float* fcW  = (const float*)d_in[13];
    const float* fcb  = (const float*)d_in[14];
    const float* fccW = (const float*)d_in[15];
    const float* fccb = (const float*)d_in[16];
    const float* mlpW = (const float*)d_in[17];
    const float* mlpb = (const float*)d_in[18];
    const float* embW = (const float*)d_in[19];
    const float* embb = (const float*)d_in[20];

    float* out_s  = (float*)d_out;
    float* out_cr = out_s + (size_t)PREDL*BATCH*POSE;

    unsigned short* wsD = (unsigned short*)d_ws;
    unsigned short* wsC = wsD + 2048;

    hipLaunchKernelGGL(lstm_prep, dim3(1), dim3(256), 0, stream,
                       dWih, dWhh, dbih, dbhh, cWih, cWhh, cbih, cbhh,
                       fcW, fcb, embW, embb, wsD, wsC);
    hipLaunchKernelGGL(lstm_w2, dim3(BATCH/64), dim3(256), 0, stream,
                       obs, eWih, eWhh, ebih, ebhh, dWih, dWhh, dbih, dbhh,
                       cWih, cWhh, cbih, cbhh, fcW, fcb, fccW, fccb,
                       mlpW, mlpb, wsD, wsC, out_s, out_cr);
}

// Round 8
// 84.464 us; speedup vs baseline: 2.8682x; 1.2104x over previous
//
#include <hip/hip_runtime.h>
#include <cstddef>

#define SEQLEN 32
#define BATCH  32768
#define POSE   34
#define PREDL  15

typedef __attribute__((ext_vector_type(8))) short short8;
typedef __attribute__((ext_vector_type(4))) float f32x4;
typedef union { short8 s8; unsigned u[4]; } pk8;

#define MF(a,b,c) __builtin_amdgcn_mfma_f32_16x16x32_bf16(a,b,c,0,0,0)

__device__ __forceinline__ float sigm(float x){ return __builtin_amdgcn_rcpf(1.0f+__expf(-x)); }
__device__ __forceinline__ float tanh_(float x){ return fmaf(2.0f, __builtin_amdgcn_rcpf(1.0f+__expf(-2.0f*x)), -1.0f); }
__device__ __forceinline__ unsigned short f2bf(float f){ __bf16 b=(__bf16)f; return __builtin_bit_cast(unsigned short,b); }
__device__ __forceinline__ unsigned f22bf(float lo,float hi){ return (unsigned)f2bf(lo) | ((unsigned)f2bf(hi)<<16); }
__device__ __forceinline__ short8 zero8(){ pk8 r; r.u[0]=0;r.u[1]=0;r.u[2]=0;r.u[3]=0; return r.s8; }

// 8 consecutive global floats -> bf16x8 (one-time weight gathers)
__device__ __forceinline__ short8 g8(const float* __restrict__ p){
    pk8 r;
    float2 q0=*(const float2*)p, q1=*(const float2*)(p+2);
    float2 q2=*(const float2*)(p+4), q3=*(const float2*)(p+6);
    r.u[0]=f22bf(q0.x,q0.y); r.u[1]=f22bf(q1.x,q1.y);
    r.u[2]=f22bf(q2.x,q2.y); r.u[3]=f22bf(q3.x,q3.y);
    return r.s8;
}
// A-frag chunk1 of K64 weights: g0=[W32,W33,bias,0..] g1=Whh[0..8) g2=Whh[8..16) g3=0
__device__ __forceinline__ short8 gW1(const float* __restrict__ Wih,const float* __restrict__ Whh,
                                      const float* __restrict__ bih,const float* __restrict__ bhh,
                                      int R,int g){
    if(g==0){ pk8 r; r.u[0]=f22bf(Wih[R*34+32],Wih[R*34+33]);
              r.u[1]=(unsigned)f2bf(bih[R]+bhh[R]); r.u[2]=0; r.u[3]=0; return r.s8; }
    if(g==3) return zero8();
    return g8(&Whh[R*16 + (g==2?8:0)]);
}
// head A-frag: [W(np)[0..16) | bias@16 | 0]
__device__ __forceinline__ short8 gH(const float* __restrict__ W,const float* __restrict__ b,
                                     int np,int nvalid,int g){
    if(np>=nvalid || g==3) return zero8();
    if(g==2){ pk8 r; r.u[0]=(unsigned)f2bf(b[np]); r.u[1]=0;r.u[2]=0;r.u[3]=0; return r.s8; }
    return g8(&W[np*16 + (g==1?8:0)]);
}

// ---- B-frag builders: col = lane&15 = batch, k = 8*(lane>>4)+e ----
__device__ __forceinline__ short8 mk_b1(unsigned hp0,unsigned hp1,int lo,int g,unsigned u0g0){
    int sA=(lo+32*(g-1))&63, sB=(sA+16)&63;
    unsigned a=__shfl(hp0,sA,64), b=__shfl(hp1,sA,64);
    unsigned c=__shfl(hp0,sB,64), d=__shfl(hp1,sB,64);
    bool mid=(g==1)||(g==2);
    pk8 r;
    r.u[0]=(g==0)?u0g0:(mid?a:0u);
    r.u[1]=(g==0)?0x3F80u:(mid?b:0u);
    r.u[2]=mid?c:0u; r.u[3]=mid?d:0u;
    return r.s8;
}
__device__ __forceinline__ short8 mk_bh(unsigned hp0,unsigned hp1,int lo,int g){
    int sA=(lo+32*g)&63, sB=(sA+16)&63;
    unsigned a=__shfl(hp0,sA,64), b=__shfl(hp1,sA,64);
    unsigned c=__shfl(hp0,sB,64), d=__shfl(hp1,sB,64);
    bool lowg=(g<2);
    pk8 r;
    r.u[0]=lowg?a:(g==2?0x3F80u:0u);
    r.u[1]=lowg?b:0u; r.u[2]=lowg?c:0u; r.u[3]=lowg?d:0u;
    return r.s8;
}
// pointwise: lane owns gate dims 4g+j of its batch; c fp32-resident
__device__ __forceinline__ void pw(const f32x4 acc[4], float (&cs)[4], unsigned &hp0, unsigned &hp1){
    float hv[4];
#pragma unroll
    for(int j=0;j<4;++j){
        float iv=sigm(acc[0][j]);
        float fv=sigm(acc[1][j]);
        float gv=tanh_(acc[2][j]);
        float ov=sigm(acc[3][j]);
        float cn=fmaf(fv,cs[j],iv*gv);
        cs[j]=cn;
        hv[j]=ov*tanh_(cn);
    }
    hp0=f22bf(hv[0],hv[1]); hp1=f22bf(hv[2],hv[3]);
}

// ---- prep kernel: fold decoder & crossing weights once into workspace ----
extern "C" __global__ void lstm_prep(
    const float* __restrict__ dWih, const float* __restrict__ dWhh,
    const float* __restrict__ dbih, const float* __restrict__ dbhh,
    const float* __restrict__ cWih, const float* __restrict__ cWhh,
    const float* __restrict__ cbih, const float* __restrict__ cbhh,
    const float* __restrict__ fcW,  const float* __restrict__ fcb,
    const float* __restrict__ embW, const float* __restrict__ embb,
    unsigned short* __restrict__ wsD, unsigned short* __restrict__ wsC)
{
    int idx = blockIdx.x*256 + threadIdx.x;
    if(idx >= 2048) return;
    int k=idx&31, n=(idx>>5)&15, gt=idx>>9;
    int R=gt*16+n;
    float vD=0.f, vC=0.f;
    if(k<16){ vD=dWhh[R*16+k];
        for(int p=0;p<34;++p) vD=fmaf(dWih[R*34+p],fcW[p*16+k],vD); }
    else if(k==16){ vD=dbih[R]+dbhh[R];
        for(int p=0;p<34;++p) vD=fmaf(dWih[R*34+p],fcb[p],vD); }
    if(k<2){ for(int p=0;p<34;++p) vC=fmaf(cWih[R*34+p],embW[2*p+k],vC); }
    else if(k==2){ vC=cbih[R]+cbhh[R];
        for(int p=0;p<34;++p) vC=fmaf(cWih[R*34+p],embb[p],vC); }
    else if(k>=8&&k<24) vC=cWhh[R*16+(k-8)];
    wsD[idx]=f2bf(vD); wsC[idx]=f2bf(vC);
}

extern "C" __global__ void __launch_bounds__(256,2) lstm_w3(
    const float* __restrict__ obs_s,
    const float* __restrict__ eWih, const float* __restrict__ eWhh,
    const float* __restrict__ ebih, const float* __restrict__ ebhh,
    const float* __restrict__ dWih, const float* __restrict__ dWhh,
    const float* __restrict__ dbih, const float* __restrict__ dbhh,
    const float* __restrict__ cWih, const float* __restrict__ cWhh,
    const float* __restrict__ cbih, const float* __restrict__ cbhh,
    const float* __restrict__ fcW,  const float* __restrict__ fcb,
    const float* __restrict__ fccW, const float* __restrict__ fccb,
    const float* __restrict__ mlpW, const float* __restrict__ mlpb,
    const unsigned short* __restrict__ wsD, const unsigned short* __restrict__ wsC,
    float* __restrict__ out_s, float* __restrict__ out_cr)
{
    __shared__ unsigned xt4[4][4][320];   // per-wave: 4 step-slots x (16 rows x 20 words)

    const int tid=threadIdx.x;
    const int l=tid&63;
    const int wv=tid>>6;
    const int lo=l&15, g=l>>4;
    const int pb=blockIdx.x*64 + wv*16;
    const f32x4 z4={0.f,0.f,0.f,0.f};
    unsigned* XT=&xt4[wv][0][0];

    // staging index precompute: flat pair idx i2 = l + 64*it ; row=i2/17, w=i2%17
    unsigned pofs[5]; int wofs[5];
#pragma unroll
    for(int it=0; it<5; ++it){
        int i2=l+64*it;
        int r=i2/17, w=i2-r*17;
        pofs[it]=(unsigned)((pb+r)*17+w);
        wofs[it]=r*20+w;
    }

    // encoder weight A-frags (one-time gathers)
    short8 wEa[4], wEb[4];
#pragma unroll
    for(int ti=0;ti<4;++ti){
        int R=ti*16+lo;
        wEa[ti]=g8(&eWih[R*34+8*g]);
        wEb[ti]=gW1(eWih,eWhh,ebih,ebhh,R,g);
    }

    float cS[4]={0.f,0.f,0.f,0.f};
    unsigned hp0=0u, hp1=0u;

    // two named 4-step register buffers (20 float2 each)
    float2 RA[4][5], RB[4][5];

    auto ldblk=[&](float2 (&R)[4][5], int t0){
#pragma unroll
        for(int s=0;s<4;++s){
            const float2* base=(const float2*)obs_s + (size_t)(t0+s)*(BATCH*17);
#pragma unroll
            for(int it=0;it<5;++it)
                if(it<4 || l<16) R[s][it]=base[pofs[it]];
        }
    };
    auto wrblk=[&](const float2 (&R)[4][5]){
#pragma unroll
        for(int s=0;s<4;++s)
#pragma unroll
            for(int it=0;it<5;++it)
                if(it<4 || l<16) XT[s*320+wofs[it]]=f22bf(R[s][it].x,R[s][it].y);
    };
    auto rdfrag=[&](int s, short8 &b, unsigned &tw){
        b=*(const short8*)&XT[s*320+lo*20+4*g];
        tw=XT[s*320+lo*20+16];
    };
    auto enc_compute=[&](short8 b0, unsigned tail){
        short8 b1=mk_b1(hp0,hp1,lo,g,tail);
        f32x4 acc[4];
#pragma unroll
        for(int ti=0;ti<4;++ti){
            f32x4 c0=MF(wEa[ti],b0,z4);
            acc[ti]=MF(wEb[ti],b1,c0);
        }
        pw(acc,cS,hp0,hp1);
    };

    // ---- encoder: 8 blocks of 4 steps; loads issued one full block ahead ----
    short8 fbQ=zero8(); unsigned ftQ=0u;        // saved x(31) fragment for s0 peel
    ldblk(RA,0);
    ldblk(RB,4);
#pragma unroll
    for(int kb=0;kb<8;++kb){
        if(kb&1){
            wrblk(RB);                           // consume RB (loaded 1 block ago)
            if(kb+2<8) ldblk(RB,4*(kb+2));       // refill for block kb+2
        } else {
            wrblk(RA);
            if(kb+2<8) ldblk(RA,4*(kb+2));
        }
        short8 fb; unsigned ft;
        rdfrag(0,fb,ft);
#pragma unroll
        for(int i=0;i<4;++i){
            short8 nfb=zero8(); unsigned nft=0u;
            if(i<3) rdfrag(i+1,nfb,nft);
            if(kb==7 && i==3){ fbQ=fb; ftQ=ft; }
            enc_compute(fb,ft);
            fb=nfb; ft=nft;
        }
    }

    // ---- decoder weights -> VGPRs ----
    short8 wDe[4], wCp[4];
#pragma unroll
    for(int ti=0;ti<4;++ti){
        wDe[ti]=*(const short8*)&wsD[(ti*16+lo)*32+8*g];
        wCp[ti]=*(const short8*)&wsC[(ti*16+lo)*32+8*g];
    }
    short8 wFc[3], wMl, wFCc;
#pragma unroll
    for(int nt=0;nt<3;++nt) wFc[nt]=gH(fcW,fcb,nt*16+lo,34,g);
    wMl =gH(mlpW,mlpb,lo,16,g);
    wFCc=gH(fccW,fccb,lo,2,g);

    // hc = mlp(h_enc)
    unsigned hcp0,hcp1;
    {
        short8 bhE=mk_bh(hp0,hp1,lo,g);
        f32x4 o=MF(wMl,bhE,z4);
        hcp0=f22bf(o[0],o[1]); hcp1=f22bf(o[2],o[3]);
    }
    float cC[4]={0.f,0.f,0.f,0.f};
    unsigned pp=0u;
    short8 bH;

    auto dec_tail=[&](int s, const f32x4 (&aC)[4], const f32x4 (&aD)[4]){
        pw(aC,cC,hcp0,hcp1);
        pw(aD,cS,hp0,hp1);
        short8 bHC=mk_bh(hcp0,hcp1,lo,g);
        f32x4 zz=MF(wFCc,bHC,z4);
        float z0=zz[0], z1=zz[1];
        float mx=fmaxf(z0,z1);
        float e0=__expf(z0-mx), e1=__expf(z1-mx);
        float rs=__builtin_amdgcn_rcpf(e0+e1);
        float p0=e0*rs, p1=e1*rs;
        pp=f22bf(p0,p1);
        if(g==0)
            ((float2*)out_cr)[(size_t)s*BATCH+pb+lo]=make_float2(p0,p1);
        bH=mk_bh(hp0,hp1,lo,g);
        float* po = out_s + ((size_t)s*BATCH + pb + lo)*POSE;
        f32x4 o0=MF(wFc[0],bH,z4);
        f32x4 o1=MF(wFc[1],bH,z4);
        *(float2*)(po+4*g)   =make_float2(o0[0],o0[1]);
        *(float2*)(po+4*g+2) =make_float2(o0[2],o0[3]);
        *(float2*)(po+16+4*g)  =make_float2(o1[0],o1[1]);
        *(float2*)(po+16+4*g+2)=make_float2(o1[2],o1[3]);
        f32x4 o2=MF(wFc[2],bH,z4);
        if(g==0) *(float2*)(po+32)=make_float2(o2[0],o2[1]);
    };

    // ---- s=0 (peeled: original K=64 weights, inputs = obs[31] from fbQ/ftQ) ----
    {
        f32x4 aC[4], aD[4];
        {
            short8 wa[4], wb[4];
#pragma unroll
            for(int ti=0;ti<4;++ti){
                int R=ti*16+lo;
                wa[ti]=g8(&cWih[R*34+8*g]);
                wb[ti]=gW1(cWih,cWhh,cbih,cbhh,R,g);
            }
            short8 b1=mk_b1(hcp0,hcp1,lo,g,ftQ);
#pragma unroll
            for(int ti=0;ti<4;++ti){
                f32x4 c0=MF(wa[ti],fbQ,z4);
                aC[ti]=MF(wb[ti],b1,c0);
            }
        }
        {
            short8 wa[4], wb[4];
#pragma unroll
            for(int ti=0;ti<4;++ti){
                int R=ti*16+lo;
                wa[ti]=g8(&dWih[R*34+8*g]);
                wb[ti]=gW1(dWih,dWhh,dbih,dbhh,R,g);
            }
            short8 b1=mk_b1(hp0,hp1,lo,g,ftQ);
#pragma unroll
            for(int ti=0;ti<4;++ti){
                f32x4 c0=MF(wa[ti],fbQ,z4);
                aD[ti]=MF(wb[ti],b1,c0);
            }
        }
        dec_tail(0,aC,aD);
    }
    // ---- s=1..14 : folded K=32 cells, zero LDS, zero barriers ----
    for(int s=1;s<PREDL;++s){
        short8 bC=mk_b1(hcp0,hcp1,lo,g,pp);
        f32x4 aC[4], aD[4];
#pragma unroll
        for(int ti=0;ti<4;++ti) aD[ti]=MF(wDe[ti],bH,z4);
#pragma unroll
        for(int ti=0;ti<4;++ti) aC[ti]=MF(wCp[ti],bC,z4);
        dec_tail(s,aC,aD);
    }
}

extern "C" void kernel_launch(void* const* d_in, const int* in_sizes, int n_in,
                              void* d_out, int out_size, void* d_ws, size_t ws_size,
                              hipStream_t stream)
{
    const float* obs  = (const float*)d_in[0];
    const float* eWih = (const float*)d_in[1];
    const float* eWhh = (const float*)d_in[2];
    const float* ebih = (const float*)d_in[3];
    const float* ebhh = (const float*)d_in[4];
    const float* dWih = (const float*)d_in[5];
    const float* dWhh = (const float*)d_in[6];
    const float* dbih = (const float*)d_in[7];
    const float* dbhh = (const float*)d_in[8];
    const float* cWih = (const float*)d_in[9];
    const float* cWhh = (const float*)d_in[10];
    const float* cbih = (const float*)d_in[11];
    const float* cbhh = (const float*)d_in[12];
    const float* fcW  = (const float*)d_in[13];
    const float* fcb  = (const float*)d_in[14];
    const float* fccW = (const float*)d_in[15];
    const float* fccb = (const float*)d_in[16];
    const float* mlpW = (const float*)d_in[17];
    const float* mlpb = (const float*)d_in[18];
    const float* embW = (const float*)d_in[19];
    const float* embb = (const float*)d_in[20];

    float* out_s  = (float*)d_out;
    float* out_cr = out_s + (size_t)PREDL*BATCH*POSE;

    unsigned short* wsD = (unsigned short*)d_ws;
    unsigned short* wsC = wsD + 2048;

    hipLaunchKernelGGL(lstm_prep, dim3(8), dim3(256), 0, stream,
                       dWih, dWhh, dbih, dbhh, cWih, cWhh, cbih, cbhh,
                       fcW, fcb, embW, embb, wsD, wsC);
    hipLaunchKernelGGL(lstm_w3, dim3(BATCH/64), dim3(256), 0, stream,
                       obs, eWih, eWhh, ebih, ebhh, dWih, dWhh, dbih, dbhh,
                       cWih, cWhh, cbih, cbhh, fcW, fcb, fccW, fccb,
                       mlpW, mlpb, wsD, wsC, out_s, out_cr);
}

// Round 9
// 68.484 us; speedup vs baseline: 3.5374x; 1.2333x over previous
//
#include <hip/hip_runtime.h>
#include <cstddef>

#define SEQLEN 32
#define BATCH  32768
#define POSE   34
#define PREDL  15
#define LOG2E  1.4426950408889634f
#define K2E    2.8853901817779268f

typedef __attribute__((ext_vector_type(8))) short short8;
typedef __attribute__((ext_vector_type(4))) float f32x4;
typedef union { short8 s8; unsigned u[4]; } pk8;

#define MF(a,b,c) __builtin_amdgcn_mfma_f32_16x16x32_bf16(a,b,c,0,0,0)
#define EXP2(x)  __builtin_amdgcn_exp2f(x)
#define RCP(x)   __builtin_amdgcn_rcpf(x)

__device__ __forceinline__ unsigned short f2bf(float f){ __bf16 b=(__bf16)f; return __builtin_bit_cast(unsigned short,b); }
__device__ __forceinline__ unsigned f22bf(float lo,float hi){ return (unsigned)f2bf(lo) | ((unsigned)f2bf(hi)<<16); }
__device__ __forceinline__ short8 zero8(){ pk8 r; r.u[0]=0;r.u[1]=0;r.u[2]=0;r.u[3]=0; return r.s8; }
__device__ __forceinline__ float scGT(int gt){ return (gt==2)?K2E:LOG2E; }

// 8 consecutive floats * s -> bf16x8 (one-time weight gathers)
__device__ __forceinline__ short8 g8s(const float* __restrict__ p, float s){
    pk8 r;
    r.u[0]=f22bf(p[0]*s,p[1]*s); r.u[1]=f22bf(p[2]*s,p[3]*s);
    r.u[2]=f22bf(p[4]*s,p[5]*s); r.u[3]=f22bf(p[6]*s,p[7]*s);
    return r.s8;
}

// trans-reduced pointwise: accs pre-scaled (i,f,o by log2e; g by 2log2e), bias included
__device__ __forceinline__ void pw4(const f32x4 (&ac)[4], float (&cs)[4],
                                    unsigned &hp0, unsigned &hp1){
    float hv[4];
#pragma unroll
    for(int j=0;j<4;++j){
        float A=EXP2(-ac[0][j]);            // sigmoid(i) = 1/(1+A)
        float C=EXP2(-ac[1][j]);            // sigmoid(f) = 1/(1+C)
        float B=EXP2( ac[2][j]);            // tanh(g) = (B-1)/(B+1)
        float O=EXP2(-ac[3][j]);            // sigmoid(o) = 1/(1+O)
        float u=1.f+A, w=1.f+C, v=B+1.f, Bm=B-1.f;
        float t1=u*v;
        float num=fmaf(cs[j], t1, Bm*w);    // c' num over common denom u*v*w
        float cn=num*RCP(t1*w);
        cs[j]=cn;
        float E=EXP2(K2E*cn);               // tanh(c') = (E-1)/(E+1)
        hv[j]=(E-1.f)*RCP((1.f+O)*(E+1.f));
    }
    hp0=f22bf(hv[0],hv[1]); hp1=f22bf(hv[2],hv[3]);
}

// ---- prep: fold decoder/crossing weights, pre-scaled, into workspace ----
extern "C" __global__ void lstm_prep(
    const float* __restrict__ dWih, const float* __restrict__ dWhh,
    const float* __restrict__ dbih, const float* __restrict__ dbhh,
    const float* __restrict__ cWih, const float* __restrict__ cWhh,
    const float* __restrict__ cbih, const float* __restrict__ cbhh,
    const float* __restrict__ fcW,  const float* __restrict__ fcb,
    const float* __restrict__ embW, const float* __restrict__ embb,
    float* __restrict__ wsBD, float* __restrict__ wsBC,
    unsigned short* __restrict__ wsDh, unsigned short* __restrict__ wsCh,
    unsigned short* __restrict__ wsCp)
{
    int idx = blockIdx.x*256 + threadIdx.x;
    if(idx < 1024){
        int R=idx>>4, k=idx&15;
        float s=scGT(R>>4);
        float vD=dWhh[R*16+k];
        for(int p=0;p<34;++p) vD=fmaf(dWih[R*34+p],fcW[p*16+k],vD);
        wsDh[idx]=f2bf(vD*s);
        wsCh[idx]=f2bf(cWhh[R*16+k]*s);
    }
    if(idx < 128){
        int R=idx>>1, k=idx&1;
        float s=scGT(R>>4);
        float v=0.f;
        for(int p=0;p<34;++p) v=fmaf(cWih[R*34+p],embW[2*p+k],v);
        wsCp[idx]=f2bf(v*s);
    }
    if(idx < 64){
        int R=idx;
        float s=scGT(R>>4);
        float vD=dbih[R]+dbhh[R], vC=cbih[R]+cbhh[R];
        for(int p=0;p<34;++p){ vD=fmaf(dWih[R*34+p],fcb[p],vD); vC=fmaf(cWih[R*34+p],embb[p],vC); }
        wsBD[idx]=vD*s; wsBC[idx]=vC*s;
    }
}

extern "C" __global__ void __launch_bounds__(256,2) lstm_w4(
    const float* __restrict__ obs_s,
    const float* __restrict__ eWih, const float* __restrict__ eWhh,
    const float* __restrict__ ebih, const float* __restrict__ ebhh,
    const float* __restrict__ dWih, const float* __restrict__ dWhh,
    const float* __restrict__ dbih, const float* __restrict__ dbhh,
    const float* __restrict__ cWih, const float* __restrict__ cWhh,
    const float* __restrict__ cbih, const float* __restrict__ cbhh,
    const float* __restrict__ fcW,  const float* __restrict__ fcb,
    const float* __restrict__ fccW, const float* __restrict__ fccb,
    const float* __restrict__ mlpW, const float* __restrict__ mlpb,
    const float* __restrict__ wsBD, const float* __restrict__ wsBC,
    const unsigned short* __restrict__ wsDh, const unsigned short* __restrict__ wsCh,
    const unsigned short* __restrict__ wsCp,
    float* __restrict__ out_s, float* __restrict__ out_cr)
{
    __shared__ unsigned xt4[4][4][320];   // per-wave: 4 step-slots x (16 rows x 20 words)

    const int tid=threadIdx.x;
    const int l=tid&63;
    const int wv=tid>>6;
    const int lo=l&15, g=l>>4;
    const int pb=blockIdx.x*64 + wv*16;
    unsigned* XT=&xt4[wv][0][0];

    // staging index precompute (R8 pattern)
    unsigned pofs[5]; int wofs[5];
#pragma unroll
    for(int it=0; it<5; ++it){
        int i2=l+64*it;
        int r=i2/17, w=i2-r*17;
        pofs[it]=(unsigned)((pb+r)*17+w);
        wofs[it]=r*20+w;
    }

    // ---- encoder weights: A-frags, pre-scaled; bias as C-frag ----
    short8 wEx[4], wEhT[4]; f32x4 biasE[4];
#pragma unroll
    for(int gt=0;gt<4;++gt){
        float s=scGT(gt);
        int R=gt*16+lo;
        wEx[gt]=g8s(&eWih[R*34+8*g], s);
        pk8 r2;
        r2.u[0]=f22bf(eWhh[R*16+4*g]*s,   eWhh[R*16+4*g+1]*s);
        r2.u[1]=f22bf(eWhh[R*16+4*g+2]*s, eWhh[R*16+4*g+3]*s);
        r2.u[2]=(g==0)? f22bf(eWih[R*34+32]*s, eWih[R*34+33]*s) : 0u;
        r2.u[3]=0u;
        wEhT[gt]=r2.s8;
        float4 ba=*(const float4*)&ebih[gt*16+4*g];
        float4 bb=*(const float4*)&ebhh[gt*16+4*g];
        biasE[gt]=f32x4{(ba.x+bb.x)*s,(ba.y+bb.y)*s,(ba.z+bb.z)*s,(ba.w+bb.w)*s};
    }

    float cS[4]={0.f,0.f,0.f,0.f};
    unsigned hp0=0u, hp1=0u;

    float2 RA[4][5], RB[4][5];
    auto ldblk=[&](float2 (&R)[4][5], int t0){
#pragma unroll
        for(int s=0;s<4;++s){
            const float2* base=(const float2*)obs_s + (size_t)(t0+s)*(BATCH*17);
#pragma unroll
            for(int it=0;it<5;++it)
                if(it<4 || l<16) R[s][it]=base[pofs[it]];
        }
    };
    auto wrblk=[&](const float2 (&R)[4][5]){
#pragma unroll
        for(int s=0;s<4;++s)
#pragma unroll
            for(int it=0;it<5;++it)
                if(it<4 || l<16) XT[s*320+wofs[it]]=f22bf(R[s][it].x,R[s][it].y);
    };
    auto rdfrag=[&](int s, short8 &b, unsigned &tw){
        b=*(const short8*)&XT[s*320+lo*20+4*g];
        tw=XT[s*320+lo*20+16];
    };
    auto enc_compute=[&](short8 b0, unsigned tw){
        pk8 bh; bh.u[0]=hp0; bh.u[1]=hp1; bh.u[2]=(g==0)?tw:0u; bh.u[3]=0u;
        f32x4 acc[4];
#pragma unroll
        for(int gt=0;gt<4;++gt){
            f32x4 cx=MF(wEx[gt], b0, biasE[gt]);     // x-part + bias (off-chain)
            acc[gt]=MF(wEhT[gt], bh.s8, cx);         // h + x-tail (on-chain, lane-local!)
        }
        pw4(acc, cS, hp0, hp1);
    };

    // ---- encoder: 8 blocks of 4 steps, loads one block ahead ----
    short8 fbQ=zero8(); unsigned ftQ=0u;
    ldblk(RA,0);
    ldblk(RB,4);
#pragma unroll
    for(int kb=0;kb<8;++kb){
        if(kb&1){ wrblk(RB); if(kb+2<8) ldblk(RB,4*(kb+2)); }
        else    { wrblk(RA); if(kb+2<8) ldblk(RA,4*(kb+2)); }
        short8 fb; unsigned ft;
        rdfrag(0,fb,ft);
#pragma unroll
        for(int i=0;i<4;++i){
            short8 nfb=zero8(); unsigned nft=0u;
            if(i<3) rdfrag(i+1,nfb,nft);
            if(kb==7 && i==3){ fbQ=fb; ftQ=ft; }
            enc_compute(fb,ft);
            fb=nfb; ft=nft;
        }
    }

    // ---- decoder weights -> VGPRs (folded, pre-scaled) ----
    short8 wDh[4], wCA[4]; f32x4 biasD[4], biasC[4];
#pragma unroll
    for(int gt=0;gt<4;++gt){
        int R=gt*16+lo;
        uint2 qd=*(const uint2*)&wsDh[R*16+4*g];
        pk8 rd; rd.u[0]=qd.x; rd.u[1]=qd.y; rd.u[2]=0u; rd.u[3]=0u;
        wDh[gt]=rd.s8;
        uint2 qc=*(const uint2*)&wsCh[R*16+4*g];
        pk8 rc; rc.u[0]=qc.x; rc.u[1]=qc.y;
        rc.u[2]=(g==0)? *(const unsigned*)&wsCp[R*2] : 0u; rc.u[3]=0u;
        wCA[gt]=rc.s8;
        biasD[gt]=*(const f32x4*)&wsBD[gt*16+4*g];
        biasC[gt]=*(const f32x4*)&wsBC[gt*16+4*g];
    }
    // head weights (unscaled) + bias C-frags
    short8 wF[3]; f32x4 fcbF[3];
#pragma unroll
    for(int nt=0;nt<3;++nt){
        int np=nt*16+lo;
        if(np<POSE){
            pk8 r;
            r.u[0]=f22bf(fcW[np*16+4*g],   fcW[np*16+4*g+1]);
            r.u[1]=f22bf(fcW[np*16+4*g+2], fcW[np*16+4*g+3]);
            r.u[2]=0u; r.u[3]=0u;
            wF[nt]=r.s8;
        } else wF[nt]=zero8();
#pragma unroll
        for(int j=0;j<4;++j){
            int row=nt*16+4*g+j;
            fcbF[nt][j]=(row<POSE)? fcb[row] : 0.f;
        }
    }
    short8 wFC, wM; f32x4 fccC, mlpbF;
    if(lo<2){
        pk8 r;
        r.u[0]=f22bf(fccW[lo*16+4*g],   fccW[lo*16+4*g+1]);
        r.u[1]=f22bf(fccW[lo*16+4*g+2], fccW[lo*16+4*g+3]);
        r.u[2]=0u; r.u[3]=0u; wFC=r.s8;
    } else wFC=zero8();
    fccC=(g==0)? f32x4{fccb[0],fccb[1],0.f,0.f} : f32x4{0.f,0.f,0.f,0.f};
    {
        pk8 r;
        r.u[0]=f22bf(mlpW[lo*16+4*g],   mlpW[lo*16+4*g+1]);
        r.u[1]=f22bf(mlpW[lo*16+4*g+2], mlpW[lo*16+4*g+3]);
        r.u[2]=0u; r.u[3]=0u; wM=r.s8;
        mlpbF=*(const f32x4*)&mlpb[4*g];
    }

    // hc = mlp(h_enc) + mlpb
    unsigned hcp0,hcp1;
    {
        pk8 bh; bh.u[0]=hp0; bh.u[1]=hp1; bh.u[2]=0u; bh.u[3]=0u;
        f32x4 o=MF(wM,bh.s8,mlpbF);
        hcp0=f22bf(o[0],o[1]); hcp1=f22bf(o[2],o[3]);
    }
    float cC[4]={0.f,0.f,0.f,0.f};
    unsigned pp=0u;

    auto dec_tail=[&](int s, const f32x4 (&aC)[4], const f32x4 (&aD)[4]){
        pw4(aD,cS,hp0,hp1);                 // decoder cell pointwise (independent chain)
        pw4(aC,cC,hcp0,hcp1);               // crossing pointwise
        // fcc: z = hc_new @ fccW.T + fccb (rows 0,1 -> g==0, j=0,1)
        pk8 bhc; bhc.u[0]=hcp0; bhc.u[1]=hcp1; bhc.u[2]=0u; bhc.u[3]=0u;
        f32x4 zz=MF(wFC,bhc.s8,fccC);
        float z0=zz[0], z1=zz[1];
        float mx=fmaxf(z0,z1);
        float e0=EXP2(LOG2E*(z0-mx)), e1=EXP2(LOG2E*(z1-mx));
        float rs=RCP(e0+e1);
        float p0=e0*rs, p1=e1*rs;
        unsigned ppn=f22bf(p0,p1);
        if(g==0)
            ((float2*)out_cr)[(size_t)s*BATCH+pb+lo]=make_float2(p0,p1);
        pp=(unsigned)__shfl((int)ppn, lo, 64);      // broadcast batch-lo's p to all its lanes
        // fc head + output
        pk8 bh; bh.u[0]=hp0; bh.u[1]=hp1; bh.u[2]=0u; bh.u[3]=0u;
        float* po = out_s + ((size_t)s*BATCH + pb + lo)*POSE;
        f32x4 o0=MF(wF[0],bh.s8,fcbF[0]);
        f32x4 o1=MF(wF[1],bh.s8,fcbF[1]);
        *(float2*)(po+4*g)     =make_float2(o0[0],o0[1]);
        *(float2*)(po+4*g+2)   =make_float2(o0[2],o0[3]);
        *(float2*)(po+16+4*g)  =make_float2(o1[0],o1[1]);
        *(float2*)(po+16+4*g+2)=make_float2(o1[2],o1[3]);
        f32x4 o2=MF(wF[2],bh.s8,fcbF[2]);
        if(g==0) *(float2*)(po+32)=make_float2(o2[0],o2[1]);
    };

    // ---- s=0 (peeled: original weights, pre-scaled on gather; inputs obs[31]) ----
    {
        f32x4 aC[4], aD[4];
#pragma unroll
        for(int gt=0;gt<4;++gt){
            float s=scGT(gt);
            int R=gt*16+lo;
            // crossing cell: x-part + (hc | tail)
            short8 a1=g8s(&cWih[R*34+8*g], s);
            pk8 a2;
            a2.u[0]=f22bf(cWhh[R*16+4*g]*s,   cWhh[R*16+4*g+1]*s);
            a2.u[1]=f22bf(cWhh[R*16+4*g+2]*s, cWhh[R*16+4*g+3]*s);
            a2.u[2]=(g==0)? f22bf(cWih[R*34+32]*s, cWih[R*34+33]*s) : 0u;
            a2.u[3]=0u;
            float4 ba=*(const float4*)&cbih[gt*16+4*g];
            float4 bb=*(const float4*)&cbhh[gt*16+4*g];
            f32x4 bc0={(ba.x+bb.x)*s,(ba.y+bb.y)*s,(ba.z+bb.z)*s,(ba.w+bb.w)*s};
            pk8 bhc; bhc.u[0]=hcp0; bhc.u[1]=hcp1; bhc.u[2]=(g==0)?ftQ:0u; bhc.u[3]=0u;
            f32x4 cx=MF(a1,fbQ,bc0);
            aC[gt]=MF(a2.s8,bhc.s8,cx);
            // decoder cell
            short8 d1=g8s(&dWih[R*34+8*g], s);
            pk8 d2;
            d2.u[0]=f22bf(dWhh[R*16+4*g]*s,   dWhh[R*16+4*g+1]*s);
            d2.u[1]=f22bf(dWhh[R*16+4*g+2]*s, dWhh[R*16+4*g+3]*s);
            d2.u[2]=(g==0)? f22bf(dWih[R*34+32]*s, dWih[R*34+33]*s) : 0u;
            d2.u[3]=0u;
            float4 da=*(const float4*)&dbih[gt*16+4*g];
            float4 db=*(const float4*)&dbhh[gt*16+4*g];
            f32x4 bd0={(da.x+db.x)*s,(da.y+db.y)*s,(da.z+db.z)*s,(da.w+db.w)*s};
            pk8 bhd; bhd.u[0]=hp0; bhd.u[1]=hp1; bhd.u[2]=(g==0)?ftQ:0u; bhd.u[3]=0u;
            f32x4 dx=MF(d1,fbQ,bd0);
            aD[gt]=MF(d2.s8,bhd.s8,dx);
        }
        dec_tail(0,aC,aD);
    }
    // ---- s=1..14: folded cells, lane-local, zero LDS/barriers/shuffles (but p-bcast) --
    for(int s=1;s<PREDL;++s){
        pk8 bd; bd.u[0]=hp0; bd.u[1]=hp1; bd.u[2]=0u; bd.u[3]=0u;
        pk8 bc; bc.u[0]=hcp0; bc.u[1]=hcp1; bc.u[2]=(g==0)?pp:0u; bc.u[3]=0u;
        f32x4 aC[4], aD[4];
#pragma unroll
        for(int gt=0;gt<4;++gt) aD[gt]=MF(wDh[gt],bd.s8,biasD[gt]);
#pragma unroll
        for(int gt=0;gt<4;++gt) aC[gt]=MF(wCA[gt],bc.s8,biasC[gt]);
        dec_tail(s,aC,aD);
    }
}

extern "C" void kernel_launch(void* const* d_in, const int* in_sizes, int n_in,
                              void* d_out, int out_size, void* d_ws, size_t ws_size,
                              hipStream_t stream)
{
    const float* obs  = (const float*)d_in[0];
    const float* eWih = (const float*)d_in[1];
    const float* eWhh = (const float*)d_in[2];
    const float* ebih = (const float*)d_in[3];
    const float* ebhh = (const float*)d_in[4];
    const float* dWih = (const float*)d_in[5];
    const float* dWhh = (const float*)d_in[6];
    const float* dbih = (const float*)d_in[7];
    const float* dbhh = (const float*)d_in[8];
    const float* cWih = (const float*)d_in[9];
    const float* cWhh = (const float*)d_in[10];
    const float* cbih = (const float*)d_in[11];
    const float* cbhh = (const float*)d_in[12];
    const float* fcW  = (const float*)d_in[13];
    const float* fcb  = (const float*)d_in[14];
    const float* fccW = (const float*)d_in[15];
    const float* fccb = (const float*)d_in[16];
    const float* mlpW = (const float*)d_in[17];
    const float* mlpb = (const float*)d_in[18];
    const float* embW = (const float*)d_in[19];
    const float* embb = (const float*)d_in[20];

    float* out_s  = (float*)d_out;
    float* out_cr = out_s + (size_t)PREDL*BATCH*POSE;

    float* wsBD = (float*)d_ws;                       // 64 f32
    float* wsBC = wsBD + 64;                          // 64 f32
    unsigned short* wsDh = (unsigned short*)(wsBC+64);// 1024 bf16
    unsigned short* wsCh = wsDh + 1024;               // 1024 bf16
    unsigned short* wsCp = wsCh + 1024;               // 128 bf16

    hipLaunchKernelGGL(lstm_prep, dim3(4), dim3(256), 0, stream,
                       dWih, dWhh, dbih, dbhh, cWih, cWhh, cbih, cbhh,
                       fcW, fcb, embW, embb, wsBD, wsBC, wsDh, wsCh, wsCp);
    hipLaunchKernelGGL(lstm_w4, dim3(BATCH/64), dim3(256), 0, stream,
                       obs, eWih, eWhh, ebih, ebhh, dWih, dWhh, dbih, dbhh,
                       cWih, cWhh, cbih, cbhh, fcW, fcb, fccW, fccb,
                       mlpW, mlpb, wsBD, wsBC, wsDh, wsCh, wsCp,
                       out_s, out_cr);
}

// Round 10
// 64.507 us; speedup vs baseline: 3.7556x; 1.0617x over previous
//
#include <hip/hip_runtime.h>
#include <cstddef>

#define SEQLEN 32
#define BATCH  32768
#define POSE   34
#define PREDL  15
#define LOG2E  1.4426950408889634f
#define K2E    2.8853901817779268f

typedef __attribute__((ext_vector_type(8))) short short8;
typedef __attribute__((ext_vector_type(4))) float f32x4;
typedef union { short8 s8; unsigned u[4]; } pk8;

#define MF(a,b,c) __builtin_amdgcn_mfma_f32_16x16x32_bf16(a,b,c,0,0,0)
#define EXP2(x)  __builtin_amdgcn_exp2f(x)
#define RCP(x)   __builtin_amdgcn_rcpf(x)

__device__ __forceinline__ unsigned short f2bf(float f){ __bf16 b=(__bf16)f; return __builtin_bit_cast(unsigned short,b); }
__device__ __forceinline__ unsigned f22bf(float lo,float hi){ return (unsigned)f2bf(lo) | ((unsigned)f2bf(hi)<<16); }
__device__ __forceinline__ short8 zero8(){ pk8 r; r.u[0]=0;r.u[1]=0;r.u[2]=0;r.u[3]=0; return r.s8; }
__device__ __forceinline__ float scGT(int gt){ return (gt==2)?K2E:LOG2E; }

__device__ __forceinline__ short8 g8s(const float* __restrict__ p, float s){
    pk8 r;
    r.u[0]=f22bf(p[0]*s,p[1]*s); r.u[1]=f22bf(p[2]*s,p[3]*s);
    r.u[2]=f22bf(p[4]*s,p[5]*s); r.u[3]=f22bf(p[6]*s,p[7]*s);
    return r.s8;
}

// packed trans-reduced pointwise: non-trans ops vectorized (v_pk_*), 7 trans/elem
__device__ __forceinline__ void pw4v(const f32x4 (&ac)[4], f32x4 &cs,
                                     unsigned &hp0, unsigned &hp1){
    f32x4 A,C,B,O;
#pragma unroll
    for(int j=0;j<4;++j){
        A[j]=EXP2(-ac[0][j]); C[j]=EXP2(-ac[1][j]);
        B[j]=EXP2( ac[2][j]); O[j]=EXP2(-ac[3][j]);
    }
    const f32x4 one={1.f,1.f,1.f,1.f};
    f32x4 u=one+A, w=one+C, v=B+one, Bm=B-one;
    f32x4 t1=u*v;
    f32x4 num=cs*t1+Bm*w;
    f32x4 den=t1*w;
    f32x4 rd_,E,rh;
#pragma unroll
    for(int j=0;j<4;++j) rd_[j]=RCP(den[j]);
    f32x4 cn=num*rd_;
    cs=cn;
#pragma unroll
    for(int j=0;j<4;++j) E[j]=EXP2(K2E*cn[j]);
    f32x4 hd=(one+O)*(E+one);
#pragma unroll
    for(int j=0;j<4;++j) rh[j]=RCP(hd[j]);
    f32x4 hv=(E-one)*rh;
    hp0=f22bf(hv[0],hv[1]); hp1=f22bf(hv[2],hv[3]);
}

// ---- prep: fold decoder/crossing weights, pre-scaled, into workspace ----
extern "C" __global__ void lstm_prep(
    const float* __restrict__ dWih, const float* __restrict__ dWhh,
    const float* __restrict__ dbih, const float* __restrict__ dbhh,
    const float* __restrict__ cWih, const float* __restrict__ cWhh,
    const float* __restrict__ cbih, const float* __restrict__ cbhh,
    const float* __restrict__ fcW,  const float* __restrict__ fcb,
    const float* __restrict__ embW, const float* __restrict__ embb,
    float* __restrict__ wsBD, float* __restrict__ wsBC,
    unsigned short* __restrict__ wsDh, unsigned short* __restrict__ wsCh,
    unsigned short* __restrict__ wsCp)
{
    int idx = blockIdx.x*256 + threadIdx.x;
    if(idx < 1024){
        int R=idx>>4, k=idx&15;
        float s=scGT(R>>4);
        float vD=dWhh[R*16+k];
        for(int p=0;p<34;++p) vD=fmaf(dWih[R*34+p],fcW[p*16+k],vD);
        wsDh[idx]=f2bf(vD*s);
        wsCh[idx]=f2bf(cWhh[R*16+k]*s);
    }
    if(idx < 128){
        int R=idx>>1, k=idx&1;
        float s=scGT(R>>4);
        float v=0.f;
        for(int p=0;p<34;++p) v=fmaf(cWih[R*34+p],embW[2*p+k],v);
        wsCp[idx]=f2bf(v*s);
    }
    if(idx < 64){
        int R=idx;
        float s=scGT(R>>4);
        float vD=dbih[R]+dbhh[R], vC=cbih[R]+cbhh[R];
        for(int p=0;p<34;++p){ vD=fmaf(dWih[R*34+p],fcb[p],vD); vC=fmaf(cWih[R*34+p],embb[p],vC); }
        wsBD[idx]=vD*s; wsBC[idx]=vC*s;
    }
}

extern "C" __global__ void __launch_bounds__(256,2) lstm_w5(
    const float* __restrict__ obs_s,
    const float* __restrict__ eWih, const float* __restrict__ eWhh,
    const float* __restrict__ ebih, const float* __restrict__ ebhh,
    const float* __restrict__ dWih, const float* __restrict__ dWhh,
    const float* __restrict__ dbih, const float* __restrict__ dbhh,
    const float* __restrict__ cWih, const float* __restrict__ cWhh,
    const float* __restrict__ cbih, const float* __restrict__ cbhh,
    const float* __restrict__ fcW,  const float* __restrict__ fcb,
    const float* __restrict__ fccW, const float* __restrict__ fccb,
    const float* __restrict__ mlpW, const float* __restrict__ mlpb,
    const float* __restrict__ wsBD, const float* __restrict__ wsBC,
    const unsigned short* __restrict__ wsDh, const unsigned short* __restrict__ wsCh,
    const unsigned short* __restrict__ wsCp,
    float* __restrict__ out_s, float* __restrict__ out_cr)
{
    __shared__ unsigned xt4[4][4][320];   // per-wave: 4 step-slots x (16 rows x 20 words)

    const int tid=threadIdx.x;
    const int l=tid&63;
    const int wv=tid>>6;
    const int lo=l&15, g=l>>4;
    const int pb=blockIdx.x*64 + wv*16;
    unsigned* XT=&xt4[wv][0][0];

    unsigned pofs[5]; int wofs[5];
#pragma unroll
    for(int it=0; it<5; ++it){
        int i2=l+64*it;
        int r=i2/17, w=i2-r*17;
        pofs[it]=(unsigned)((pb+r)*17+w);
        wofs[it]=r*20+w;
    }

    // ---- encoder weights: A-frags, pre-scaled; bias as C-frag ----
    short8 wEx[4], wEhT[4]; f32x4 biasE[4];
#pragma unroll
    for(int gt=0;gt<4;++gt){
        float s=scGT(gt);
        int R=gt*16+lo;
        wEx[gt]=g8s(&eWih[R*34+8*g], s);
        pk8 r2;
        r2.u[0]=f22bf(eWhh[R*16+4*g]*s,   eWhh[R*16+4*g+1]*s);
        r2.u[1]=f22bf(eWhh[R*16+4*g+2]*s, eWhh[R*16+4*g+3]*s);
        r2.u[2]=(g==0)? f22bf(eWih[R*34+32]*s, eWih[R*34+33]*s) : 0u;
        r2.u[3]=0u;
        wEhT[gt]=r2.s8;
        float4 ba=*(const float4*)&ebih[gt*16+4*g];
        float4 bb=*(const float4*)&ebhh[gt*16+4*g];
        biasE[gt]=f32x4{(ba.x+bb.x)*s,(ba.y+bb.y)*s,(ba.z+bb.z)*s,(ba.w+bb.w)*s};
    }

    f32x4 cS={0.f,0.f,0.f,0.f};
    unsigned hp0=0u, hp1=0u;

    float2 RA[4][5];
    auto ldblk=[&](float2 (&R)[4][5], int t0){
#pragma unroll
        for(int s=0;s<4;++s){
            const float2* base=(const float2*)obs_s + (size_t)(t0+s)*(BATCH*17);
#pragma unroll
            for(int it=0;it<5;++it)
                if(it<4 || l<16) R[s][it]=base[pofs[it]];
        }
    };
    auto wrblk=[&](const float2 (&R)[4][5]){
#pragma unroll
        for(int s=0;s<4;++s)
#pragma unroll
            for(int it=0;it<5;++it)
                if(it<4 || l<16) XT[s*320+wofs[it]]=f22bf(R[s][it].x,R[s][it].y);
    };

    // ---- encoder: 8 blocks of 4 steps; x-MFMAs hoisted off the chain ----
    short8 fbQ=zero8(); unsigned ftQ=0u;
    ldblk(RA,0);
#pragma unroll
    for(int kb=0;kb<8;++kb){
        wrblk(RA);
        if(kb+1<8) ldblk(RA,4*(kb+1));        // refill for next block (WAR, in-order)
        short8 bx[4]; unsigned tw[4];
#pragma unroll
        for(int s=0;s<4;++s){
            bx[s]=*(const short8*)&XT[s*320+lo*20+4*g];
            tw[s]=XT[s*320+lo*20+16];
        }
        f32x4 cx[4][4];
#pragma unroll
        for(int s=0;s<4;++s)
#pragma unroll
            for(int gt=0;gt<4;++gt)
                cx[s][gt]=MF(wEx[gt],bx[s],biasE[gt]);   // off-chain x-part + bias
        if(kb==7){ fbQ=bx[3]; ftQ=tw[3]; }
#pragma unroll
        for(int s=0;s<4;++s){                            // pure-register chain loop
            pk8 bh; bh.u[0]=hp0; bh.u[1]=hp1; bh.u[2]=(g==0)?tw[s]:0u; bh.u[3]=0u;
            f32x4 acc[4];
#pragma unroll
            for(int gt=0;gt<4;++gt) acc[gt]=MF(wEhT[gt],bh.s8,cx[s][gt]);
            pw4v(acc,cS,hp0,hp1);
        }
    }

    // ---- decoder weights -> VGPRs (folded, pre-scaled) ----
    short8 wDh[4], wCA[4]; f32x4 biasD[4], biasC[4];
#pragma unroll
    for(int gt=0;gt<4;++gt){
        int R=gt*16+lo;
        uint2 qd=*(const uint2*)&wsDh[R*16+4*g];
        pk8 rd; rd.u[0]=qd.x; rd.u[1]=qd.y; rd.u[2]=0u; rd.u[3]=0u;
        wDh[gt]=rd.s8;
        uint2 qc=*(const uint2*)&wsCh[R*16+4*g];
        pk8 rc; rc.u[0]=qc.x; rc.u[1]=qc.y;
        rc.u[2]=(g==0)? *(const unsigned*)&wsCp[R*2] : 0u; rc.u[3]=0u;
        wCA[gt]=rc.s8;
        biasD[gt]=*(const f32x4*)&wsBD[gt*16+4*g];
        biasC[gt]=*(const f32x4*)&wsBC[gt*16+4*g];
    }
    short8 wF[3]; f32x4 fcbF[3];
#pragma unroll
    for(int nt=0;nt<3;++nt){
        int np=nt*16+lo;
        if(np<POSE){
            pk8 r;
            r.u[0]=f22bf(fcW[np*16+4*g],   fcW[np*16+4*g+1]);
            r.u[1]=f22bf(fcW[np*16+4*g+2], fcW[np*16+4*g+3]);
            r.u[2]=0u; r.u[3]=0u;
            wF[nt]=r.s8;
        } else wF[nt]=zero8();
#pragma unroll
        for(int j=0;j<4;++j){
            int row=nt*16+4*g+j;
            fcbF[nt][j]=(row<POSE)? fcb[row] : 0.f;
        }
    }
    short8 wFC, wM; f32x4 fccC, mlpbF;
    if(lo<2){
        pk8 r;
        r.u[0]=f22bf(fccW[lo*16+4*g],   fccW[lo*16+4*g+1]);
        r.u[1]=f22bf(fccW[lo*16+4*g+2], fccW[lo*16+4*g+3]);
        r.u[2]=0u; r.u[3]=0u; wFC=r.s8;
    } else wFC=zero8();
    fccC=(g==0)? f32x4{fccb[0],fccb[1],0.f,0.f} : f32x4{0.f,0.f,0.f,0.f};
    {
        pk8 r;
        r.u[0]=f22bf(mlpW[lo*16+4*g],   mlpW[lo*16+4*g+1]);
        r.u[1]=f22bf(mlpW[lo*16+4*g+2], mlpW[lo*16+4*g+3]);
        r.u[2]=0u; r.u[3]=0u; wM=r.s8;
        mlpbF=*(const f32x4*)&mlpb[4*g];
    }

    // hc = mlp(h_enc) + mlpb
    unsigned hcp0,hcp1;
    {
        pk8 bh; bh.u[0]=hp0; bh.u[1]=hp1; bh.u[2]=0u; bh.u[3]=0u;
        f32x4 o=MF(wM,bh.s8,mlpbF);
        hcp0=f22bf(o[0],o[1]); hcp1=f22bf(o[2],o[3]);
    }
    f32x4 cC={0.f,0.f,0.f,0.f};
    unsigned pp=0u;

    auto dec_tail=[&](int s, const f32x4 (&aC)[4], const f32x4 (&aD)[4]){
        pw4v(aD,cS,hp0,hp1);
        pw4v(aC,cC,hcp0,hcp1);
        pk8 bhc; bhc.u[0]=hcp0; bhc.u[1]=hcp1; bhc.u[2]=0u; bhc.u[3]=0u;
        f32x4 zz=MF(wFC,bhc.s8,fccC);
        float z0=zz[0], z1=zz[1];
        float mx=fmaxf(z0,z1);
        float e0=EXP2(LOG2E*(z0-mx)), e1=EXP2(LOG2E*(z1-mx));
        float rs=RCP(e0+e1);
        float p0=e0*rs, p1=e1*rs;
        unsigned ppn=f22bf(p0,p1);
        if(g==0)
            ((float2*)out_cr)[(size_t)s*BATCH+pb+lo]=make_float2(p0,p1);
        pp=(unsigned)__shfl((int)ppn, lo, 64);
        pk8 bh; bh.u[0]=hp0; bh.u[1]=hp1; bh.u[2]=0u; bh.u[3]=0u;
        float* po = out_s + ((size_t)s*BATCH + pb + lo)*POSE;
        f32x4 o0=MF(wF[0],bh.s8,fcbF[0]);
        f32x4 o1=MF(wF[1],bh.s8,fcbF[1]);
        *(float2*)(po+4*g)     =make_float2(o0[0],o0[1]);
        *(float2*)(po+4*g+2)   =make_float2(o0[2],o0[3]);
        *(float2*)(po+16+4*g)  =make_float2(o1[0],o1[1]);
        *(float2*)(po+16+4*g+2)=make_float2(o1[2],o1[3]);
        f32x4 o2=MF(wF[2],bh.s8,fcbF[2]);
        if(g==0) *(float2*)(po+32)=make_float2(o2[0],o2[1]);
    };

    // ---- s=0 (peeled: original weights, pre-scaled on gather; inputs obs[31]) ----
    {
        f32x4 aC[4], aD[4];
#pragma unroll
        for(int gt=0;gt<4;++gt){
            float s=scGT(gt);
            int R=gt*16+lo;
            short8 a1=g8s(&cWih[R*34+8*g], s);
            pk8 a2;
            a2.u[0]=f22bf(cWhh[R*16+4*g]*s,   cWhh[R*16+4*g+1]*s);
            a2.u[1]=f22bf(cWhh[R*16+4*g+2]*s, cWhh[R*16+4*g+3]*s);
            a2.u[2]=(g==0)? f22bf(cWih[R*34+32]*s, cWih[R*34+33]*s) : 0u;
            a2.u[3]=0u;
            float4 ba=*(const float4*)&cbih[gt*16+4*g];
            float4 bb=*(const float4*)&cbhh[gt*16+4*g];
            f32x4 bc0={(ba.x+bb.x)*s,(ba.y+bb.y)*s,(ba.z+bb.z)*s,(ba.w+bb.w)*s};
            pk8 bhc; bhc.u[0]=hcp0; bhc.u[1]=hcp1; bhc.u[2]=(g==0)?ftQ:0u; bhc.u[3]=0u;
            f32x4 cx=MF(a1,fbQ,bc0);
            aC[gt]=MF(a2.s8,bhc.s8,cx);
            short8 d1=g8s(&dWih[R*34+8*g], s);
            pk8 d2;
            d2.u[0]=f22bf(dWhh[R*16+4*g]*s,   dWhh[R*16+4*g+1]*s);
            d2.u[1]=f22bf(dWhh[R*16+4*g+2]*s, dWhh[R*16+4*g+3]*s);
            d2.u[2]=(g==0)? f22bf(dWih[R*34+32]*s, dWih[R*34+33]*s) : 0u;
            d2.u[3]=0u;
            float4 da=*(const float4*)&dbih[gt*16+4*g];
            float4 db=*(const float4*)&dbhh[gt*16+4*g];
            f32x4 bd0={(da.x+db.x)*s,(da.y+db.y)*s,(da.z+db.z)*s,(da.w+db.w)*s};
            pk8 bhd; bhd.u[0]=hp0; bhd.u[1]=hp1; bhd.u[2]=(g==0)?ftQ:0u; bhd.u[3]=0u;
            f32x4 dx=MF(d1,fbQ,bd0);
            aD[gt]=MF(d2.s8,bhd.s8,dx);
        }
        dec_tail(0,aC,aD);
    }
    // ---- s=1..14: folded cells, lane-local, pure-register ----
    for(int s=1;s<PREDL;++s){
        pk8 bd; bd.u[0]=hp0; bd.u[1]=hp1; bd.u[2]=0u; bd.u[3]=0u;
        pk8 bc; bc.u[0]=hcp0; bc.u[1]=hcp1; bc.u[2]=(g==0)?pp:0u; bc.u[3]=0u;
        f32x4 aC[4], aD[4];
#pragma unroll
        for(int gt=0;gt<4;++gt) aD[gt]=MF(wDh[gt],bd.s8,biasD[gt]);
#pragma unroll
        for(int gt=0;gt<4;++gt) aC[gt]=MF(wCA[gt],bc.s8,biasC[gt]);
        dec_tail(s,aC,aD);
    }
}

extern "C" void kernel_launch(void* const* d_in, const int* in_sizes, int n_in,
                              void* d_out, int out_size, void* d_ws, size_t ws_size,
                              hipStream_t stream)
{
    const float* obs  = (const float*)d_in[0];
    const float* eWih = (const float*)d_in[1];
    const float* eWhh = (const float*)d_in[2];
    const float* ebih = (const float*)d_in[3];
    const float* ebhh = (const float*)d_in[4];
    const float* dWih = (const float*)d_in[5];
    const float* dWhh = (const float*)d_in[6];
    const float* dbih = (const float*)d_in[7];
    const float* dbhh = (const float*)d_in[8];
    const float* cWih = (const float*)d_in[9];
    const float* cWhh = (const float*)d_in[10];
    const float* cbih = (const float*)d_in[11];
    const float* cbhh = (const float*)d_in[12];
    const float* fcW  = (const float*)d_in[13];
    const float* fcb  = (const float*)d_in[14];
    const float* fccW = (const float*)d_in[15];
    const float* fccb = (const float*)d_in[16];
    const float* mlpW = (const float*)d_in[17];
    const float* mlpb = (const float*)d_in[18];
    const float* embW = (const float*)d_in[19];
    const float* embb = (const float*)d_in[20];

    float* out_s  = (float*)d_out;
    float* out_cr = out_s + (size_t)PREDL*BATCH*POSE;

    float* wsBD = (float*)d_ws;
    float* wsBC = wsBD + 64;
    unsigned short* wsDh = (unsigned short*)(wsBC+64);
    unsigned short* wsCh = wsDh + 1024;
    unsigned short* wsCp = wsCh + 1024;

    hipLaunchKernelGGL(lstm_prep, dim3(4), dim3(256), 0, stream,
                       dWih, dWhh, dbih, dbhh, cWih, cWhh, cbih, cbhh,
                       fcW, fcb, embW, embb, wsBD, wsBC, wsDh, wsCh, wsCp);
    hipLaunchKernelGGL(lstm_w5, dim3(BATCH/64), dim3(256), 0, stream,
                       obs, eWih, eWhh, ebih, ebhh, dWih, dWhh, dbih, dbhh,
                       cWih, cWhh, cbih, cbhh, fcW, fcb, fccW, fccb,
                       mlpW, mlpb, wsBD, wsBC, wsDh, wsCh, wsCp,
                       out_s, out_cr);
}